// Round 9
// baseline (11722.988 us; speedup 1.0000x reference)
//
#include <hip/hip_runtime.h>
#include <cmath>

#define LN_EPS 1e-5f

// posenc in f64 (matches an f64-promoted numpy reference to ~1e-12).
__device__ __forceinline__ double posenc_d(int s, int d) {
    double expo = (double)(d & ~1) * (1.0 / 512.0);
    double ang = (double)s * exp(-expo * 9.210340371976184); // s / 10000^expo
    return (d & 1) ? cos(ang) : sin(ang);
}

// ---------------------------------------------------------------------------
// sentinel: fills first 4096 d_out floats with v (diagnostic channel).
// ---------------------------------------------------------------------------
__global__ __launch_bounds__(256) void sentinel_kernel(float* out, float v) {
    out[blockIdx.x * 256 + threadIdx.x] = v;
}

// ---------------------------------------------------------------------------
// x = E + posenc.  F64OUT: store f64 (layout A) or f32 (layout B).
// ---------------------------------------------------------------------------
template <bool F64OUT>
__global__ __launch_bounds__(256) void xgen_kernel(const float* __restrict__ E,
                                                   void* __restrict__ x) {
    const int idx = blockIdx.x * 256 + threadIdx.x;
    const int s = idx >> 9, d = idx & 511;
    const double v = (double)E[idx] + posenc_d(s, d);
    if (F64OUT) ((double*)x)[idx] = v;
    else        ((float*)x)[idx] = (float)v;
}

// ---------------------------------------------------------------------------
// Q/K/V projection, ONE head, f64 accumulation.
// grid (64 mblocks, 1, 3): z selects Q/K/V.  Q,K stored f64; V stored f32.
// XT = double (layout A) or float (layout B, promoted on load).
// ---------------------------------------------------------------------------
template <typename XT>
__device__ __forceinline__ void qkv_body(const XT* __restrict__ x,
                                         const float* __restrict__ Wq,
                                         const float* __restrict__ Wk,
                                         const float* __restrict__ Wv,
                                         double* __restrict__ Qd,
                                         double* __restrict__ Kd,
                                         float* __restrict__ Vf,
                                         int head) {
    const int z = blockIdx.z;
    const float* W = (z == 0) ? Wq : (z == 1) ? Wk : Wv;
    const long wbase = (long)head * 512 * 64;

    __shared__ double sA[64][17];
    __shared__ float sB[16][65];
    const int tx = threadIdx.x, ty = threadIdx.y;
    const int t = ty * 16 + tx;
    const int m0 = blockIdx.x * 64;
    const int ar = t >> 2, ac = (t & 3) << 2;

    double acc[4][4] = {};
    for (int k0 = 0; k0 < 512; k0 += 16) {
        #pragma unroll
        for (int u = 0; u < 4; ++u)
            sA[ar][ac + u] = (double)x[(long)(m0 + ar) * 512 + k0 + ac + u];
        #pragma unroll
        for (int u = 0; u < 4; ++u)
            sB[ty][(tx << 2) + u] = W[wbase + (long)(k0 + ty) * 64 + (tx << 2) + u];
        __syncthreads();
        #pragma unroll
        for (int kk = 0; kk < 16; ++kk) {
            double a[4], b[4];
            #pragma unroll
            for (int i = 0; i < 4; ++i) a[i] = sA[(ty << 2) + i][kk];
            #pragma unroll
            for (int j = 0; j < 4; ++j) b[j] = (double)sB[kk][(tx << 2) + j];
            #pragma unroll
            for (int i = 0; i < 4; ++i)
                #pragma unroll
                for (int j = 0; j < 4; ++j)
                    acc[i][j] = fma(a[i], b[j], acc[i][j]);
        }
        __syncthreads();
    }
    #pragma unroll
    for (int i = 0; i < 4; ++i)
        #pragma unroll
        for (int j = 0; j < 4; ++j) {
            const long o = (long)(m0 + (ty << 2) + i) * 64 + (tx << 2) + j;
            if (z == 0) Qd[o] = acc[i][j];
            else if (z == 1) Kd[o] = acc[i][j];
            else Vf[o] = (float)acc[i][j];
        }
}

__global__ __launch_bounds__(256) void qkv64_kernel(const double* x,
                                                    const float* Wq, const float* Wk,
                                                    const float* Wv, double* Qd,
                                                    double* Kd, float* Vf, int head) {
    qkv_body<double>(x, Wq, Wk, Wv, Qd, Kd, Vf, head);
}
__global__ __launch_bounds__(256) void qkv32_kernel(const float* x,
                                                    const float* Wq, const float* Wk,
                                                    const float* Wv, double* Qd,
                                                    double* Kd, float* Vf, int head) {
    qkv_body<float>(x, Wq, Wk, Wv, Qd, Kd, Vf, head);
}

// ---------------------------------------------------------------------------
// Flash attention, one head, grid (128 qblocks of 32 rows), block 16x16.
// Q,K f64; scores f64; softmax state f64; PV f32. Writes Zcat (= d_out) f32
// cols [h*64, h*64+64).
// ---------------------------------------------------------------------------
__global__ __launch_bounds__(256) void flash_kernel(const double* __restrict__ Qd,
                                                    const double* __restrict__ Kd,
                                                    const float* __restrict__ Vf,
                                                    float* __restrict__ Zcat,
                                                    int head) {
    const int qb = blockIdx.x;
    __shared__ double sQ[32][65];
    __shared__ double sK[32][65];
    __shared__ double sP[32][33];
    __shared__ float sV[32][65];
    __shared__ double m_s[32], l_s[32];
    __shared__ float a_s[32];

    const int tx = threadIdx.x, ty = threadIdx.y;
    const int t = ty * 16 + tx;

    #pragma unroll
    for (int c = 0; c < 8; ++c) {
        int idx = t + 256 * c, row = idx >> 6, col = idx & 63;
        sQ[row][col] = Qd[(long)(qb * 32 + row) * 64 + col];
    }
    if (t < 32) { m_s[t] = -INFINITY; l_s[t] = 0.0; }
    float acc[2][4] = {};
    __syncthreads();

    for (int kb = 0; kb < 128; ++kb) {
        const int base = kb * 32;
        #pragma unroll
        for (int c = 0; c < 8; ++c) {
            int idx = t + 256 * c, row = idx >> 6, col = idx & 63;
            sK[row][col] = Kd[(long)(base + row) * 64 + col];
            sV[row][col] = Vf[(long)(base + row) * 64 + col];
        }
        __syncthreads();

        // scores: 32x32 tile, 2x2 per thread, f64
        double s2[2][2] = {};
        for (int d = 0; d < 64; ++d) {
            double qa[2], kk[2];
            #pragma unroll
            for (int i = 0; i < 2; ++i) qa[i] = sQ[(ty << 1) + i][d];
            #pragma unroll
            for (int j = 0; j < 2; ++j) kk[j] = sK[(tx << 1) + j][d];
            #pragma unroll
            for (int i = 0; i < 2; ++i)
                #pragma unroll
                for (int j = 0; j < 2; ++j)
                    s2[i][j] = fma(qa[i], kk[j], s2[i][j]);
        }
        #pragma unroll
        for (int i = 0; i < 2; ++i)
            #pragma unroll
            for (int j = 0; j < 2; ++j)
                sP[(ty << 1) + i][(tx << 1) + j] = s2[i][j] * 0.125;
        __syncthreads();

        // online softmax: lane per row (f64)
        if (t < 32) {
            const int row = t;
            double rm = -INFINITY;
            for (int c = 0; c < 32; ++c) rm = fmax(rm, sP[row][c]);
            double nm = fmax(m_s[row], rm);
            double al = exp(m_s[row] - nm);   // first block: exp(-inf)=0
            double sum = 0.0;
            for (int c = 0; c < 32; ++c) {
                double p = exp(sP[row][c] - nm);
                sP[row][c] = p;
                sum += p;
            }
            l_s[row] = l_s[row] * al + sum;
            m_s[row] = nm;
            a_s[row] = (float)al;
        }
        __syncthreads();

        #pragma unroll
        for (int i = 0; i < 2; ++i) {
            const float al = a_s[(ty << 1) + i];
            #pragma unroll
            for (int j = 0; j < 4; ++j) acc[i][j] *= al;
        }
        for (int k = 0; k < 32; ++k) {
            float p[2], v[4];
            #pragma unroll
            for (int i = 0; i < 2; ++i) p[i] = (float)sP[(ty << 1) + i][k];
            #pragma unroll
            for (int j = 0; j < 4; ++j) v[j] = sV[k][(tx << 2) + j];
            #pragma unroll
            for (int i = 0; i < 2; ++i)
                #pragma unroll
                for (int j = 0; j < 4; ++j)
                    acc[i][j] = fmaf(p[i], v[j], acc[i][j]);
        }
        __syncthreads();
    }

    #pragma unroll
    for (int i = 0; i < 2; ++i) {
        const int row = qb * 32 + (ty << 1) + i;
        const float inv = (float)(1.0 / l_s[(ty << 1) + i]);
        #pragma unroll
        for (int j = 0; j < 4; ++j)
            Zcat[(long)row * 512 + head * 64 + (tx << 2) + j] =
                acc[i][j] * inv;
    }
}

// ---------------------------------------------------------------------------
// Z1 = LN(Zcat @ WO + (E+posenc)) -> f32.  32 rows x all 512 cols per block.
// ---------------------------------------------------------------------------
__global__ __launch_bounds__(256) void grl1_kernel(const float* __restrict__ A,
                                                   const float* __restrict__ B,
                                                   const float* __restrict__ E,
                                                   const float* __restrict__ g,
                                                   const float* __restrict__ be,
                                                   float* __restrict__ Z1) {
    __shared__ float sA[32][17];
    __shared__ float sB[16][513];
    __shared__ float red[32][33];
    __shared__ float mean_s[32], rstd_s[32];

    const int t = threadIdx.x;
    const int tx = t & 31, ty = t >> 5;   // 32 x 8
    const int r0 = blockIdx.x * 32;

    float acc[4][16] = {};
    for (int k0 = 0; k0 < 512; k0 += 16) {
        {
            int idx = t, row = idx >> 4, col = idx & 15;
            sA[row][col] = A[(long)(r0 + row) * 512 + k0 + col];
            idx = t + 256; row = idx >> 4; col = idx & 15;
            sA[row][col] = A[(long)(r0 + row) * 512 + k0 + col];
        }
        #pragma unroll
        for (int c = 0; c < 32; ++c) {
            int idx = t + 256 * c, row = idx >> 9, col = idx & 511;
            sB[row][col] = B[(long)(k0 + row) * 512 + col];
        }
        __syncthreads();
        #pragma unroll
        for (int kk = 0; kk < 16; ++kk) {
            float a[4], b[16];
            #pragma unroll
            for (int i = 0; i < 4; ++i) a[i] = sA[(ty << 2) + i][kk];
            #pragma unroll
            for (int jj = 0; jj < 16; ++jj) b[jj] = sB[kk][tx + 32 * jj];
            #pragma unroll
            for (int i = 0; i < 4; ++i)
                #pragma unroll
                for (int jj = 0; jj < 16; ++jj)
                    acc[i][jj] = fmaf(a[i], b[jj], acc[i][jj]);
        }
        __syncthreads();
    }

    #pragma unroll
    for (int i = 0; i < 4; ++i) {
        const int gr = r0 + (ty << 2) + i;
        #pragma unroll
        for (int jj = 0; jj < 16; ++jj) {
            const int col = tx + 32 * jj;
            acc[i][jj] += (float)((double)E[(long)gr * 512 + col]
                                  + posenc_d(gr, col));
        }
    }
    #pragma unroll
    for (int i = 0; i < 4; ++i) {
        float p = 0.0f;
        #pragma unroll
        for (int jj = 0; jj < 16; ++jj) p += acc[i][jj];
        red[(ty << 2) + i][tx] = p;
    }
    __syncthreads();
    if (t < 32) {
        float s = 0.0f;
        for (int x2 = 0; x2 < 32; ++x2) s += red[t][x2];
        mean_s[t] = s * (1.0f / 512.0f);
    }
    __syncthreads();
    #pragma unroll
    for (int i = 0; i < 4; ++i) {
        const float mu = mean_s[(ty << 2) + i];
        float p = 0.0f;
        #pragma unroll
        for (int jj = 0; jj < 16; ++jj) {
            float d = acc[i][jj] - mu;
            p += d * d;
        }
        red[(ty << 2) + i][tx] = p;
    }
    __syncthreads();
    if (t < 32) {
        float s = 0.0f;
        for (int x2 = 0; x2 < 32; ++x2) s += red[t][x2];
        rstd_s[t] = rsqrtf(s * (1.0f / 512.0f) + LN_EPS);
    }
    __syncthreads();
    #pragma unroll
    for (int i = 0; i < 4; ++i) {
        const int rr = (ty << 2) + i, gr = r0 + rr;
        const float mu = mean_s[rr], rs = rstd_s[rr];
        #pragma unroll
        for (int jj = 0; jj < 16; ++jj) {
            const int col = tx + 32 * jj;
            Z1[(long)gr * 512 + col] =
                (acc[i][jj] - mu) * rs * g[col] + be[col];
        }
    }
}

// ---------------------------------------------------------------------------
// FFN1: Hff = relu(Z1c @ W1 + b1), f32.  grid (32 ncols, rows/64).
// ---------------------------------------------------------------------------
__global__ __launch_bounds__(256) void ffn1_kernel(const float* __restrict__ A,
                                                   const float* __restrict__ W1,
                                                   const float* __restrict__ b1,
                                                   float* __restrict__ C) {
    __shared__ float sA[64][17];
    __shared__ float sB[16][65];
    const int tx = threadIdx.x, ty = threadIdx.y;
    const int t = ty * 16 + tx;
    const int m0 = blockIdx.y * 64, n0 = blockIdx.x * 64;
    const int ar = t >> 2, ac = (t & 3) << 2;

    float acc[4][4] = {};
    for (int k0 = 0; k0 < 512; k0 += 16) {
        float4 av = *(const float4*)(A + (long)(m0 + ar) * 512 + k0 + ac);
        sA[ar][ac + 0] = av.x; sA[ar][ac + 1] = av.y;
        sA[ar][ac + 2] = av.z; sA[ar][ac + 3] = av.w;
        float4 bv = *(const float4*)(W1 + (long)(k0 + ty) * 2048 + n0 + (tx << 2));
        sB[ty][(tx << 2) + 0] = bv.x; sB[ty][(tx << 2) + 1] = bv.y;
        sB[ty][(tx << 2) + 2] = bv.z; sB[ty][(tx << 2) + 3] = bv.w;
        __syncthreads();
        #pragma unroll
        for (int kk = 0; kk < 16; ++kk) {
            float a[4], b[4];
            #pragma unroll
            for (int i = 0; i < 4; ++i) a[i] = sA[(ty << 2) + i][kk];
            #pragma unroll
            for (int j = 0; j < 4; ++j) b[j] = sB[kk][(tx << 2) + j];
            #pragma unroll
            for (int i = 0; i < 4; ++i)
                #pragma unroll
                for (int j = 0; j < 4; ++j)
                    acc[i][j] = fmaf(a[i], b[j], acc[i][j]);
        }
        __syncthreads();
    }
    #pragma unroll
    for (int i = 0; i < 4; ++i)
        #pragma unroll
        for (int j = 0; j < 4; ++j) {
            const int cn = n0 + (tx << 2) + j;
            float v = acc[i][j] + b1[cn];
            C[(long)(m0 + (ty << 2) + i) * 2048 + cn] = fmaxf(v, 0.0f);
        }
}

// ---------------------------------------------------------------------------
// out = LN(Hff @ W2 + b2 + Z1c) -> FLOAT d_out.  32 rows x 512 cols per block.
// ---------------------------------------------------------------------------
__global__ __launch_bounds__(256) void grl2_kernel(const float* __restrict__ A,
                                                   const float* __restrict__ B,
                                                   const float* __restrict__ bias,
                                                   const float* __restrict__ res,
                                                   const float* __restrict__ g,
                                                   const float* __restrict__ be,
                                                   float* __restrict__ out) {
    __shared__ float sA[32][17];
    __shared__ float sB[16][513];
    __shared__ float red[32][33];
    __shared__ float mean_s[32], rstd_s[32];

    const int t = threadIdx.x;
    const int tx = t & 31, ty = t >> 5;
    const int r0 = blockIdx.x * 32;

    float acc[4][16] = {};
    for (int k0 = 0; k0 < 2048; k0 += 16) {
        {
            int idx = t, row = idx >> 4, col = idx & 15;
            sA[row][col] = A[(long)(r0 + row) * 2048 + k0 + col];
            idx = t + 256; row = idx >> 4; col = idx & 15;
            sA[row][col] = A[(long)(r0 + row) * 2048 + k0 + col];
        }
        #pragma unroll
        for (int c = 0; c < 32; ++c) {
            int idx = t + 256 * c, row = idx >> 9, col = idx & 511;
            sB[row][col] = B[(long)(k0 + row) * 512 + col];
        }
        __syncthreads();
        #pragma unroll
        for (int kk = 0; kk < 16; ++kk) {
            float a[4], b[16];
            #pragma unroll
            for (int i = 0; i < 4; ++i) a[i] = sA[(ty << 2) + i][kk];
            #pragma unroll
            for (int jj = 0; jj < 16; ++jj) b[jj] = sB[kk][tx + 32 * jj];
            #pragma unroll
            for (int i = 0; i < 4; ++i)
                #pragma unroll
                for (int jj = 0; jj < 16; ++jj)
                    acc[i][jj] = fmaf(a[i], b[jj], acc[i][jj]);
        }
        __syncthreads();
    }

    #pragma unroll
    for (int i = 0; i < 4; ++i) {
        const int gr = r0 + (ty << 2) + i;
        #pragma unroll
        for (int jj = 0; jj < 16; ++jj) {
            const int col = tx + 32 * jj;
            acc[i][jj] += bias[col] + res[(long)gr * 512 + col];
        }
    }
    #pragma unroll
    for (int i = 0; i < 4; ++i) {
        float p = 0.0f;
        #pragma unroll
        for (int jj = 0; jj < 16; ++jj) p += acc[i][jj];
        red[(ty << 2) + i][tx] = p;
    }
    __syncthreads();
    if (t < 32) {
        float s = 0.0f;
        for (int x2 = 0; x2 < 32; ++x2) s += red[t][x2];
        mean_s[t] = s * (1.0f / 512.0f);
    }
    __syncthreads();
    #pragma unroll
    for (int i = 0; i < 4; ++i) {
        const float mu = mean_s[(ty << 2) + i];
        float p = 0.0f;
        #pragma unroll
        for (int jj = 0; jj < 16; ++jj) {
            float d = acc[i][jj] - mu;
            p += d * d;
        }
        red[(ty << 2) + i][tx] = p;
    }
    __syncthreads();
    if (t < 32) {
        float s = 0.0f;
        for (int x2 = 0; x2 < 32; ++x2) s += red[t][x2];
        rstd_s[t] = rsqrtf(s * (1.0f / 512.0f) + LN_EPS);
    }
    __syncthreads();
    #pragma unroll
    for (int i = 0; i < 4; ++i) {
        const int rr = (ty << 2) + i, gr = r0 + rr;
        const float mu = mean_s[rr], rs = rstd_s[rr];
        #pragma unroll
        for (int jj = 0; jj < 16; ++jj) {
            const int col = tx + 32 * jj;
            out[(long)gr * 512 + col] =
                (acc[i][jj] - mu) * rs * g[col] + be[col];
        }
    }
}

// ---------------------------------------------------------------------------
// ws layouts (ws_size-aware; all writes stay strictly inside d_ws):
//   A (ws >= 22 MB): xd f64 @0 (16 MB) | Qd @16 (2) | Kd @18 (2) | Vf @20 (1)
//   B (ws >= 14 MB): xf f32 @0 ( 8 MB) | Qd @8  (2) | Kd @10 (2) | Vf @12 (1)
//   After attention (both): Z1 f32 @0 (8 MB), Hff f32 @8MB (4 MB) alias dead
//   regions.  Zcat lives in d_out (f32 4096x512) until grl1 consumes it.
// ---------------------------------------------------------------------------
extern "C" void kernel_launch(void* const* d_in, const int* in_sizes, int n_in,
                              void* d_out, int out_size, void* d_ws, size_t ws_size,
                              hipStream_t stream) {
    float* outf = (float*)d_out;

    static const int exp_sizes[13] = {2097152, 262144, 262144, 262144, 262144,
                                      1048576, 2048, 1048576, 512, 512, 512,
                                      512, 512};
    bool ok = (n_in == 13);
    if (ok) for (int i = 0; i < 13; ++i) if (in_sizes[i] != exp_sizes[i]) ok = false;
    if (!ok) { sentinel_kernel<<<16, 256, 0, stream>>>(outf, 1000.0f); return; }
    if (out_size != 2097152) { sentinel_kernel<<<16, 256, 0, stream>>>(outf, 2000.0f); return; }

    const bool bigws = ws_size >= (22ull << 20);
    const bool midws = ws_size >= (14ull << 20);
    if (!bigws && !midws) {
        // encode ws_size (MB) into the diagnostic channel
        sentinel_kernel<<<16, 256, 0, stream>>>(outf,
            100000.0f + (float)(ws_size >> 20));
        return;
    }

    const float* E   = (const float*)d_in[0];
    const float* Wq  = (const float*)d_in[1];
    const float* Wk  = (const float*)d_in[2];
    const float* Wv  = (const float*)d_in[3];
    const float* WO  = (const float*)d_in[4];
    const float* W1  = (const float*)d_in[5];
    const float* b1  = (const float*)d_in[6];
    const float* W2  = (const float*)d_in[7];
    const float* b2  = (const float*)d_in[8];
    const float* g1  = (const float*)d_in[9];
    const float* be1 = (const float*)d_in[10];
    const float* g2  = (const float*)d_in[11];
    const float* be2 = (const float*)d_in[12];

    char* base = (char*)d_ws;
    float* Zcat = outf;                          // scratch inside d_out
    dim3 blk2(16, 16);

    if (bigws) {
        double* xd = (double*)base;                      // 16 MB
        double* Qd = (double*)(base + (16l << 20));      // 2 MB
        double* Kd = (double*)(base + (18l << 20));      // 2 MB
        float*  Vf = (float*)(base + (20l << 20));       // 1 MB
        xgen_kernel<true><<<8192, 256, 0, stream>>>(E, xd);
        for (int h = 0; h < 8; ++h) {
            qkv64_kernel<<<dim3(64, 1, 3), blk2, 0, stream>>>(xd, Wq, Wk, Wv,
                                                              Qd, Kd, Vf, h);
            flash_kernel<<<128, blk2, 0, stream>>>(Qd, Kd, Vf, Zcat, h);
        }
    } else {
        float*  xf = (float*)base;                       // 8 MB
        double* Qd = (double*)(base + (8l << 20));       // 2 MB
        double* Kd = (double*)(base + (10l << 20));      // 2 MB
        float*  Vf = (float*)(base + (12l << 20));       // 1 MB
        xgen_kernel<false><<<8192, 256, 0, stream>>>(E, xf);
        for (int h = 0; h < 8; ++h) {
            qkv32_kernel<<<dim3(64, 1, 3), blk2, 0, stream>>>(xf, Wq, Wk, Wv,
                                                              Qd, Kd, Vf, h);
            flash_kernel<<<128, blk2, 0, stream>>>(Qd, Kd, Vf, Zcat, h);
        }
    }

    float* Z1  = (float*)base;                  // 8 MB, aliases dead x
    float* Hff = (float*)(base + (8l << 20));   // 4 MB, aliases dead x/Q/K

    grl1_kernel<<<128, 256, 0, stream>>>(Zcat, WO, E, g1, be1, Z1);

    for (int c = 0; c < 8; ++c) {
        const float* Z1c = Z1 + (long)c * 512 * 512;
        ffn1_kernel<<<dim3(32, 8), blk2, 0, stream>>>(Z1c, W1, b1, Hff);
        grl2_kernel<<<16, 256, 0, stream>>>(Hff, W2, b2, Z1c, g2, be2,
                                            outf + (long)c * 512 * 512);
    }
}

// Round 10
// 3881.155 us; speedup vs baseline: 3.0205x; 3.0205x over previous
//
#include <hip/hip_runtime.h>
#include <hip/hip_bf16.h>
#include <cmath>

typedef __hip_bfloat16 bf16;
typedef unsigned short u16;

#define LN_EPS 1e-5f

__device__ __forceinline__ float us2f(u16 u) {
    return __uint_as_float(((unsigned int)u) << 16);
}

// posenc in f64 (only f64 left in the pipeline — needed because f32 sin of
// ang up to 4095 rad has 2.4e-4 error that feeds coherently into logits).
__device__ __forceinline__ double posenc_d(int s, int d) {
    double expo = (double)(d & ~1) * (1.0 / 512.0);
    double ang = (double)s * exp(-expo * 9.210340371976184); // s / 10000^expo
    return (d & 1) ? cos(ang) : sin(ang);
}

__global__ __launch_bounds__(256) void sentinel_kernel(float* out, float v) {
    out[blockIdx.x * 256 + threadIdx.x] = v;
}

// ---------------------------------------------------------------------------
// xf = E + posenc (f64 math, f32 store).  grid 8192.
// ---------------------------------------------------------------------------
__global__ __launch_bounds__(256) void xgen_kernel(const float* __restrict__ E,
                                                   float* __restrict__ xf) {
    const int idx = blockIdx.x * 256 + threadIdx.x;
    const int s = idx >> 9, d = idx & 511;
    xf[idx] = (float)((double)E[idx] + posenc_d(s, d));
}

// ---------------------------------------------------------------------------
// Q/K/V projection for a PAIR of heads, f32. grid (64 mb, 2 hl, 3 z).
// ---------------------------------------------------------------------------
__global__ __launch_bounds__(256) void qkv2_kernel(const float* __restrict__ xf,
                                                   const float* __restrict__ Wq,
                                                   const float* __restrict__ Wk,
                                                   const float* __restrict__ Wv,
                                                   float* __restrict__ Q2,
                                                   float* __restrict__ K2,
                                                   float* __restrict__ V2,
                                                   int hp) {
    const int z = blockIdx.z, hl = blockIdx.y, head = hp * 2 + hl;
    const float* W = ((z == 0) ? Wq : (z == 1) ? Wk : Wv) + (long)head * 512 * 64;
    float* C = ((z == 0) ? Q2 : (z == 1) ? K2 : V2) + (long)hl * 4096 * 64;

    __shared__ float sA[64][17];
    __shared__ float sB[16][65];
    const int tx = threadIdx.x, ty = threadIdx.y;
    const int t = ty * 16 + tx;
    const int m0 = blockIdx.x * 64;
    const int ar = t >> 2, ac = (t & 3) << 2;

    float acc[4][4] = {};
    for (int k0 = 0; k0 < 512; k0 += 16) {
        float4 av = *(const float4*)(xf + (long)(m0 + ar) * 512 + k0 + ac);
        sA[ar][ac + 0] = av.x; sA[ar][ac + 1] = av.y;
        sA[ar][ac + 2] = av.z; sA[ar][ac + 3] = av.w;
        float4 bv = *(const float4*)(W + (long)(k0 + ty) * 64 + (tx << 2));
        sB[ty][(tx << 2) + 0] = bv.x; sB[ty][(tx << 2) + 1] = bv.y;
        sB[ty][(tx << 2) + 2] = bv.z; sB[ty][(tx << 2) + 3] = bv.w;
        __syncthreads();
        #pragma unroll
        for (int kk = 0; kk < 16; ++kk) {
            float a[4], b[4];
            #pragma unroll
            for (int i = 0; i < 4; ++i) a[i] = sA[(ty << 2) + i][kk];
            #pragma unroll
            for (int j = 0; j < 4; ++j) b[j] = sB[kk][(tx << 2) + j];
            #pragma unroll
            for (int i = 0; i < 4; ++i)
                #pragma unroll
                for (int j = 0; j < 4; ++j)
                    acc[i][j] = fmaf(a[i], b[j], acc[i][j]);
        }
        __syncthreads();
    }
    #pragma unroll
    for (int i = 0; i < 4; ++i)
        #pragma unroll
        for (int j = 0; j < 4; ++j)
            C[(long)(m0 + (ty << 2) + i) * 64 + (tx << 2) + j] = acc[i][j];
}

// ---------------------------------------------------------------------------
// Flash attention, f32, pair of heads. grid (128 qb of 32 rows, 2 hl).
// 64-col k-tiles; parallel LDS softmax; writes Zcat (d_out) cols [head*64,+64).
// ---------------------------------------------------------------------------
__global__ __launch_bounds__(256) void flash2_kernel(const float* __restrict__ Q2,
                                                     const float* __restrict__ K2,
                                                     const float* __restrict__ V2,
                                                     float* __restrict__ Zcat,
                                                     int hp) {
    const int hl = blockIdx.y, head = hp * 2 + hl, qb = blockIdx.x;
    const float* Qh = Q2 + (long)hl * 4096 * 64;
    const float* Kh = K2 + (long)hl * 4096 * 64;
    const float* Vh = V2 + (long)hl * 4096 * 64;

    __shared__ float sQ[32][65];
    __shared__ float sK[64][65];
    __shared__ float sV[64][65];
    __shared__ float sP[32][65];
    __shared__ float red[32][17];
    __shared__ float m_s[32], l_s[32], a_s[32], nm_s[32];

    const int tx = threadIdx.x, ty = threadIdx.y;
    const int t = ty * 16 + tx;
    const int r0 = ty * 2;            // 2 rows per thread
    const int c0 = tx * 4;            // 4 cols per thread

    #pragma unroll
    for (int c = 0; c < 8; ++c) {
        int idx = t + 256 * c, r = idx >> 6, col = idx & 63;
        sQ[r][col] = Qh[(long)(qb * 32 + r) * 64 + col];
    }
    if (t < 32) { m_s[t] = -INFINITY; l_s[t] = 0.0f; }
    float acc[2][4] = {};
    __syncthreads();

    for (int kb = 0; kb < 64; ++kb) {
        const int kb0 = kb * 64;
        #pragma unroll
        for (int c = 0; c < 16; ++c) {
            int idx = t + 256 * c, r = idx >> 6, col = idx & 63;
            sK[r][col] = Kh[(long)(kb0 + r) * 64 + col];
            sV[r][col] = Vh[(long)(kb0 + r) * 64 + col];
        }
        __syncthreads();

        // S = Q K^T * 0.125  (32x64 tile, 2x4/thread)
        float s[2][4] = {};
        for (int d = 0; d < 64; ++d) {
            float qa0 = sQ[r0][d], qa1 = sQ[r0 + 1][d];
            float kk[4];
            #pragma unroll
            for (int j = 0; j < 4; ++j) kk[j] = sK[c0 + j][d];
            #pragma unroll
            for (int j = 0; j < 4; ++j) {
                s[0][j] = fmaf(qa0, kk[j], s[0][j]);
                s[1][j] = fmaf(qa1, kk[j], s[1][j]);
            }
        }
        #pragma unroll
        for (int i = 0; i < 2; ++i) {
            float mx = -INFINITY;
            #pragma unroll
            for (int j = 0; j < 4; ++j) {
                s[i][j] *= 0.125f;
                mx = fmaxf(mx, s[i][j]);
            }
            red[r0 + i][tx] = mx;
        }
        __syncthreads();
        if (t < 32) {
            float mx = -INFINITY;
            #pragma unroll
            for (int u = 0; u < 16; ++u) mx = fmaxf(mx, red[t][u]);
            float nm = fmaxf(m_s[t], mx);
            a_s[t] = __expf(m_s[t] - nm);   // first block: exp(-inf)=0
            nm_s[t] = nm;
            m_s[t] = nm;
        }
        __syncthreads();
        #pragma unroll
        for (int i = 0; i < 2; ++i) {
            const float nm = nm_s[r0 + i];
            float ps = 0.0f;
            #pragma unroll
            for (int j = 0; j < 4; ++j) {
                float p = __expf(s[i][j] - nm);
                sP[r0 + i][c0 + j] = p;
                ps += p;
            }
            red[r0 + i][tx] = ps;
        }
        __syncthreads();
        if (t < 32) {
            float ss = 0.0f;
            #pragma unroll
            for (int u = 0; u < 16; ++u) ss += red[t][u];
            l_s[t] = l_s[t] * a_s[t] + ss;
        }
        __syncthreads();

        #pragma unroll
        for (int i = 0; i < 2; ++i) {
            const float al = a_s[r0 + i];
            #pragma unroll
            for (int j = 0; j < 4; ++j) acc[i][j] *= al;
        }
        for (int k = 0; k < 64; ++k) {
            float p0 = sP[r0][k], p1 = sP[r0 + 1][k];
            float v[4];
            #pragma unroll
            for (int j = 0; j < 4; ++j) v[j] = sV[k][c0 + j];
            #pragma unroll
            for (int j = 0; j < 4; ++j) {
                acc[0][j] = fmaf(p0, v[j], acc[0][j]);
                acc[1][j] = fmaf(p1, v[j], acc[1][j]);
            }
        }
        __syncthreads();
    }

    #pragma unroll
    for (int i = 0; i < 2; ++i) {
        const int row = qb * 32 + r0 + i;
        const float inv = 1.0f / l_s[r0 + i];
        #pragma unroll
        for (int j = 0; j < 4; ++j)
            Zcat[(long)row * 512 + head * 64 + c0 + j] = acc[i][j] * inv;
    }
}

// ---------------------------------------------------------------------------
// Plain f32 GEMM: C = A(Mx512) @ B(512x512).  grid (8 nb, 64 mb).
// Used for Zcat @ WO -> tmp.
// ---------------------------------------------------------------------------
__global__ __launch_bounds__(256) void wo_kernel(const float* __restrict__ A,
                                                 const float* __restrict__ B,
                                                 float* __restrict__ C) {
    __shared__ float sA[64][17];
    __shared__ float sB[16][65];
    const int tx = threadIdx.x, ty = threadIdx.y;
    const int t = ty * 16 + tx;
    const int m0 = blockIdx.y * 64, n0 = blockIdx.x * 64;
    const int ar = t >> 2, ac = (t & 3) << 2;

    float acc[4][4] = {};
    for (int k0 = 0; k0 < 512; k0 += 16) {
        float4 av = *(const float4*)(A + (long)(m0 + ar) * 512 + k0 + ac);
        sA[ar][ac + 0] = av.x; sA[ar][ac + 1] = av.y;
        sA[ar][ac + 2] = av.z; sA[ar][ac + 3] = av.w;
        float4 bv = *(const float4*)(B + (long)(k0 + ty) * 512 + n0 + (tx << 2));
        sB[ty][(tx << 2) + 0] = bv.x; sB[ty][(tx << 2) + 1] = bv.y;
        sB[ty][(tx << 2) + 2] = bv.z; sB[ty][(tx << 2) + 3] = bv.w;
        __syncthreads();
        #pragma unroll
        for (int kk = 0; kk < 16; ++kk) {
            float a[4], b[4];
            #pragma unroll
            for (int i = 0; i < 4; ++i) a[i] = sA[(ty << 2) + i][kk];
            #pragma unroll
            for (int j = 0; j < 4; ++j) b[j] = sB[kk][(tx << 2) + j];
            #pragma unroll
            for (int i = 0; i < 4; ++i)
                #pragma unroll
                for (int j = 0; j < 4; ++j)
                    acc[i][j] = fmaf(a[i], b[j], acc[i][j]);
        }
        __syncthreads();
    }
    #pragma unroll
    for (int i = 0; i < 4; ++i)
        #pragma unroll
        for (int j = 0; j < 4; ++j)
            C[(long)(m0 + (ty << 2) + i) * 512 + n0 + (tx << 2) + j] = acc[i][j];
}

// ---------------------------------------------------------------------------
// ln1: Z1 = LN(tmp + E + posenc)*g + be -> d_out (in place over Zcat).
// grid 4096 (one row per block), 256 threads, 2 cols each.
// ---------------------------------------------------------------------------
__global__ __launch_bounds__(256) void ln1_kernel(const float* __restrict__ tmp,
                                                  const float* __restrict__ E,
                                                  const float* __restrict__ g,
                                                  const float* __restrict__ be,
                                                  float* __restrict__ out) {
    const int r = blockIdx.x, t = threadIdx.x;
    const long base = (long)r * 512;
    __shared__ float red[256];

    float v0 = tmp[base + t] +
               (float)((double)E[base + t] + posenc_d(r, t));
    float v1 = tmp[base + t + 256] +
               (float)((double)E[base + t + 256] + posenc_d(r, t + 256));

    red[t] = v0 + v1; __syncthreads();
    for (int s2 = 128; s2 > 0; s2 >>= 1) {
        if (t < s2) red[t] += red[t + s2];
        __syncthreads();
    }
    const float mean = red[0] * (1.0f / 512.0f);
    __syncthreads();
    float d0 = v0 - mean, d1 = v1 - mean;
    red[t] = d0 * d0 + d1 * d1; __syncthreads();
    for (int s2 = 128; s2 > 0; s2 >>= 1) {
        if (t < s2) red[t] += red[t + s2];
        __syncthreads();
    }
    const float rs = rsqrtf(red[0] * (1.0f / 512.0f) + LN_EPS);
    out[base + t] = d0 * rs * g[t] + be[t];
    out[base + t + 256] = d1 * rs * g[t + 256] + be[t + 256];
}

// ---------------------------------------------------------------------------
// ffn1: Hff = relu(Z1c @ W1 + b1) -> bf16.  grid (32 nb, 32 mb) per 2048-row
// chunk.  A f32 lda 512, B 512x2048, C bf16 ldc 2048.
// ---------------------------------------------------------------------------
__global__ __launch_bounds__(256) void ffn1_kernel(const float* __restrict__ A,
                                                   const float* __restrict__ W1,
                                                   const float* __restrict__ b1,
                                                   bf16* __restrict__ C) {
    __shared__ float sA[64][17];
    __shared__ float sB[16][65];
    const int tx = threadIdx.x, ty = threadIdx.y;
    const int t = ty * 16 + tx;
    const int m0 = blockIdx.y * 64, n0 = blockIdx.x * 64;
    const int ar = t >> 2, ac = (t & 3) << 2;

    float acc[4][4] = {};
    for (int k0 = 0; k0 < 512; k0 += 16) {
        float4 av = *(const float4*)(A + (long)(m0 + ar) * 512 + k0 + ac);
        sA[ar][ac + 0] = av.x; sA[ar][ac + 1] = av.y;
        sA[ar][ac + 2] = av.z; sA[ar][ac + 3] = av.w;
        float4 bv = *(const float4*)(W1 + (long)(k0 + ty) * 2048 + n0 + (tx << 2));
        sB[ty][(tx << 2) + 0] = bv.x; sB[ty][(tx << 2) + 1] = bv.y;
        sB[ty][(tx << 2) + 2] = bv.z; sB[ty][(tx << 2) + 3] = bv.w;
        __syncthreads();
        #pragma unroll
        for (int kk = 0; kk < 16; ++kk) {
            float a[4], b[4];
            #pragma unroll
            for (int i = 0; i < 4; ++i) a[i] = sA[(ty << 2) + i][kk];
            #pragma unroll
            for (int j = 0; j < 4; ++j) b[j] = sB[kk][(tx << 2) + j];
            #pragma unroll
            for (int i = 0; i < 4; ++i)
                #pragma unroll
                for (int j = 0; j < 4; ++j)
                    acc[i][j] = fmaf(a[i], b[j], acc[i][j]);
        }
        __syncthreads();
    }
    #pragma unroll
    for (int i = 0; i < 4; ++i)
        #pragma unroll
        for (int j = 0; j < 4; ++j) {
            const int cn = n0 + (tx << 2) + j;
            float v = acc[i][j] + b1[cn];
            C[(long)(m0 + (ty << 2) + i) * 2048 + cn] =
                __float2bfloat16(fmaxf(v, 0.0f));
        }
}

// ---------------------------------------------------------------------------
// ffn2: U = Hff(bf16) @ W2 + b2 -> f32.  grid (8 nb, 32 mb) per chunk.
// ---------------------------------------------------------------------------
__global__ __launch_bounds__(256) void ffn2_kernel(const u16* __restrict__ A,
                                                   const float* __restrict__ W2,
                                                   const float* __restrict__ b2,
                                                   float* __restrict__ U) {
    __shared__ float sA[64][17];
    __shared__ float sB[16][65];
    const int tx = threadIdx.x, ty = threadIdx.y;
    const int t = ty * 16 + tx;
    const int m0 = blockIdx.y * 64, n0 = blockIdx.x * 64;
    const int ar = t >> 2, ac = (t & 3) << 2;

    float acc[4][4] = {};
    for (int k0 = 0; k0 < 2048; k0 += 16) {
        ushort4 av = *(const ushort4*)(A + (long)(m0 + ar) * 2048 + k0 + ac);
        sA[ar][ac + 0] = us2f(av.x); sA[ar][ac + 1] = us2f(av.y);
        sA[ar][ac + 2] = us2f(av.z); sA[ar][ac + 3] = us2f(av.w);
        float4 bv = *(const float4*)(W2 + (long)(k0 + ty) * 512 + n0 + (tx << 2));
        sB[ty][(tx << 2) + 0] = bv.x; sB[ty][(tx << 2) + 1] = bv.y;
        sB[ty][(tx << 2) + 2] = bv.z; sB[ty][(tx << 2) + 3] = bv.w;
        __syncthreads();
        #pragma unroll
        for (int kk = 0; kk < 16; ++kk) {
            float a[4], b[4];
            #pragma unroll
            for (int i = 0; i < 4; ++i) a[i] = sA[(ty << 2) + i][kk];
            #pragma unroll
            for (int j = 0; j < 4; ++j) b[j] = sB[kk][(tx << 2) + j];
            #pragma unroll
            for (int i = 0; i < 4; ++i)
                #pragma unroll
                for (int j = 0; j < 4; ++j)
                    acc[i][j] = fmaf(a[i], b[j], acc[i][j]);
        }
        __syncthreads();
    }
    #pragma unroll
    for (int i = 0; i < 4; ++i)
        #pragma unroll
        for (int j = 0; j < 4; ++j) {
            const int cn = n0 + (tx << 2) + j;
            U[(long)(m0 + (ty << 2) + i) * 512 + cn] = acc[i][j] + b2[cn];
        }
}

// ---------------------------------------------------------------------------
// ln2: out = LN(U + Z1row)*g + be -> d_out row (in place over Z1).
// grid 2048 per chunk (one row per block).
// ---------------------------------------------------------------------------
__global__ __launch_bounds__(256) void ln2_kernel(const float* __restrict__ U,
                                                  const float* __restrict__ Z1,
                                                  const float* __restrict__ g,
                                                  const float* __restrict__ be,
                                                  float* __restrict__ out) {
    const int r = blockIdx.x, t = threadIdx.x;
    const long base = (long)r * 512;
    __shared__ float red[256];

    float v0 = U[base + t] + Z1[base + t];
    float v1 = U[base + t + 256] + Z1[base + t + 256];

    red[t] = v0 + v1; __syncthreads();
    for (int s2 = 128; s2 > 0; s2 >>= 1) {
        if (t < s2) red[t] += red[t + s2];
        __syncthreads();
    }
    const float mean = red[0] * (1.0f / 512.0f);
    __syncthreads();
    float d0 = v0 - mean, d1 = v1 - mean;
    red[t] = d0 * d0 + d1 * d1; __syncthreads();
    for (int s2 = 128; s2 > 0; s2 >>= 1) {
        if (t < s2) red[t] += red[t + s2];
        __syncthreads();
    }
    const float rs = rsqrtf(red[0] * (1.0f / 512.0f) + LN_EPS);
    out[base + t] = d0 * rs * g[t] + be[t];
    out[base + t + 256] = d1 * rs * g[t + 256] + be[t + 256];
}

// ---------------------------------------------------------------------------
// ws plan (max 14 MB, proven safe by round 9's midws pass):
//   attention: xf f32 @0 (8 MB) | Q2 @8 (2 MB) | K2 @10 (2) | V2 @12 (2)
//   post-attn:  tmp f32 @0 (8 MB)
//   FFN chunk:  Hff bf16 @0 (8 MB) | U f32 @8 (4 MB)
// d_out: Zcat -> Z1 -> final out (all overwrites row-local / phase-separated).
// ---------------------------------------------------------------------------
extern "C" void kernel_launch(void* const* d_in, const int* in_sizes, int n_in,
                              void* d_out, int out_size, void* d_ws, size_t ws_size,
                              hipStream_t stream) {
    float* outf = (float*)d_out;

    static const int exp_sizes[13] = {2097152, 262144, 262144, 262144, 262144,
                                      1048576, 2048, 1048576, 512, 512, 512,
                                      512, 512};
    bool ok = (n_in == 13) && (out_size == 2097152) &&
              (ws_size >= (14ull << 20));
    if (ok) for (int i = 0; i < 13; ++i) if (in_sizes[i] != exp_sizes[i]) ok = false;
    if (!ok) { sentinel_kernel<<<16, 256, 0, stream>>>(outf, 1000.0f); return; }

    const float* E   = (const float*)d_in[0];
    const float* Wq  = (const float*)d_in[1];
    const float* Wk  = (const float*)d_in[2];
    const float* Wv  = (const float*)d_in[3];
    const float* WO  = (const float*)d_in[4];
    const float* W1  = (const float*)d_in[5];
    const float* b1  = (const float*)d_in[6];
    const float* W2  = (const float*)d_in[7];
    const float* b2  = (const float*)d_in[8];
    const float* g1  = (const float*)d_in[9];
    const float* be1 = (const float*)d_in[10];
    const float* g2  = (const float*)d_in[11];
    const float* be2 = (const float*)d_in[12];

    char* base = (char*)d_ws;
    float* xf = (float*)base;                       // 8 MB
    float* Q2 = (float*)(base + (8l << 20));        // 2 MB
    float* K2 = (float*)(base + (10l << 20));       // 2 MB
    float* V2 = (float*)(base + (12l << 20));       // 2 MB
    float* tmp = (float*)base;                      // 8 MB (xf dead)
    u16*   Hff = (u16*)base;                        // 8 MB (tmp dead)
    float* U   = (float*)(base + (8l << 20));       // 4 MB

    dim3 blk2(16, 16);

    // 1. x = E + posenc
    xgen_kernel<<<8192, 256, 0, stream>>>(E, xf);

    // 2. attention, 4 pairs of heads; Zcat accumulates in d_out (f32)
    for (int hp = 0; hp < 4; ++hp) {
        qkv2_kernel<<<dim3(64, 2, 3), blk2, 0, stream>>>(xf, Wq, Wk, Wv,
                                                         Q2, K2, V2, hp);
        flash2_kernel<<<dim3(128, 2), blk2, 0, stream>>>(Q2, K2, V2, outf, hp);
    }

    // 3. tmp = Zcat @ WO ;  Z1 = LN(tmp + x) -> d_out in place
    wo_kernel<<<dim3(8, 64), blk2, 0, stream>>>(outf, WO, tmp);
    ln1_kernel<<<4096, 256, 0, stream>>>(tmp, E, g1, be1, outf);

    // 4. FFN in 2 chunks of 2048 rows; final out in d_out in place
    for (int c = 0; c < 2; ++c) {
        const float* Z1c = outf + (long)c * 2048 * 512;
        ffn1_kernel<<<dim3(32, 32), blk2, 0, stream>>>(Z1c, W1, b1, (bf16*)Hff);
        ffn2_kernel<<<dim3(8, 32), blk2, 0, stream>>>(Hff, W2, b2, U);
        ln2_kernel<<<2048, 256, 0, stream>>>(U, Z1c, g2, be2,
                                             outf + (long)c * 2048 * 512);
    }
}

// Round 11
// 1228.921 us; speedup vs baseline: 9.5393x; 3.1582x over previous
//
#include <hip/hip_runtime.h>
#include <hip/hip_bf16.h>
#include <cmath>

typedef unsigned short u16;
#define LN_EPS 1e-5f

__device__ __forceinline__ float us2f(u16 u) {
    return __uint_as_float(((unsigned int)u) << 16);
}
__device__ __forceinline__ u16 f2us(float f) {
    __hip_bfloat16 h = __float2bfloat16(f);
    return *(u16*)&h;
}

// posenc in f64 (the only f64 left: f32 sin(up to 4095 rad) errs 2.4e-4
// coherently into logits).
__device__ __forceinline__ double posenc_d(int s, int d) {
    double expo = (double)(d & ~1) * (1.0 / 512.0);
    double ang = (double)s * exp(-expo * 9.210340371976184);
    return (d & 1) ? cos(ang) : sin(ang);
}

__global__ __launch_bounds__(256) void sentinel_kernel(float* out, float v) {
    out[blockIdx.x * 256 + threadIdx.x] = v;
}

// ---------------------------------------------------------------------------
// qkv8: x=(E+posenc) recomputed inline; one head+type per z block.
// grid (64 mb, 24).  z: type=z>>3 (0=Q,1=K,2=V), h=z&7.
// Q -> Qcat in d_out cols [h*64,+64); K -> ws f32; V -> ws bf16.
// ---------------------------------------------------------------------------
__global__ __launch_bounds__(256) void qkv8_kernel(const float* __restrict__ E,
                                                   const float* __restrict__ Wq,
                                                   const float* __restrict__ Wk,
                                                   const float* __restrict__ Wv,
                                                   float* __restrict__ Qcat,
                                                   float* __restrict__ Kws,
                                                   u16* __restrict__ Vws) {
    const int z = blockIdx.y;
    const int type = z >> 3, h = z & 7;
    const float* W = (type == 0 ? Wq : type == 1 ? Wk : Wv) + (long)h * 512 * 64;

    __shared__ float sA[64][17];
    __shared__ float sB[16][68];
    __shared__ double sFreq[512];

    const int t = threadIdx.x;
    const int tx = t & 15, ty = t >> 4;
    const int m0 = blockIdx.x * 64;
    const int ar = t >> 2, ac = (t & 3) << 2;

    sFreq[t] = exp(-((double)(t & ~1) * (1.0 / 512.0)) * 9.210340371976184);
    sFreq[t + 256] = exp(-((double)((t + 256) & ~1) * (1.0 / 512.0)) * 9.210340371976184);
    __syncthreads();

    float acc[4][4] = {};
    for (int k0 = 0; k0 < 512; k0 += 16) {
        float4 av = *(const float4*)(E + (long)(m0 + ar) * 512 + k0 + ac);
        float ax[4] = {av.x, av.y, av.z, av.w};
        #pragma unroll
        for (int u = 0; u < 4; ++u) {
            const int col = k0 + ac + u;
            double ang = (double)(m0 + ar) * sFreq[col];
            double pe = (col & 1) ? cos(ang) : sin(ang);
            sA[ar][ac + u] = (float)((double)ax[u] + pe);
        }
        *(float4*)&sB[ty][tx << 2] =
            *(const float4*)(W + (long)(k0 + ty) * 64 + (tx << 2));
        __syncthreads();
        #pragma unroll
        for (int kk = 0; kk < 16; ++kk) {
            float a0 = sA[(ty << 2) + 0][kk];
            float a1 = sA[(ty << 2) + 1][kk];
            float a2 = sA[(ty << 2) + 2][kk];
            float a3 = sA[(ty << 2) + 3][kk];
            float4 b4 = *(const float4*)&sB[kk][tx << 2];
            acc[0][0] = fmaf(a0, b4.x, acc[0][0]); acc[0][1] = fmaf(a0, b4.y, acc[0][1]);
            acc[0][2] = fmaf(a0, b4.z, acc[0][2]); acc[0][3] = fmaf(a0, b4.w, acc[0][3]);
            acc[1][0] = fmaf(a1, b4.x, acc[1][0]); acc[1][1] = fmaf(a1, b4.y, acc[1][1]);
            acc[1][2] = fmaf(a1, b4.z, acc[1][2]); acc[1][3] = fmaf(a1, b4.w, acc[1][3]);
            acc[2][0] = fmaf(a2, b4.x, acc[2][0]); acc[2][1] = fmaf(a2, b4.y, acc[2][1]);
            acc[2][2] = fmaf(a2, b4.z, acc[2][2]); acc[2][3] = fmaf(a2, b4.w, acc[2][3]);
            acc[3][0] = fmaf(a3, b4.x, acc[3][0]); acc[3][1] = fmaf(a3, b4.y, acc[3][1]);
            acc[3][2] = fmaf(a3, b4.z, acc[3][2]); acc[3][3] = fmaf(a3, b4.w, acc[3][3]);
        }
        __syncthreads();
    }

    #pragma unroll
    for (int i = 0; i < 4; ++i) {
        const int row = m0 + (ty << 2) + i;
        if (type == 0) {
            *(float4*)(Qcat + (long)row * 512 + h * 64 + (tx << 2)) =
                make_float4(acc[i][0], acc[i][1], acc[i][2], acc[i][3]);
        } else if (type == 1) {
            *(float4*)(Kws + (long)h * 4096 * 64 + (long)row * 64 + (tx << 2)) =
                make_float4(acc[i][0], acc[i][1], acc[i][2], acc[i][3]);
        } else {
            ushort4 o;
            o.x = f2us(acc[i][0]); o.y = f2us(acc[i][1]);
            o.z = f2us(acc[i][2]); o.w = f2us(acc[i][3]);
            *(ushort4*)(Vws + (long)h * 4096 * 64 + (long)row * 64 + (tx << 2)) = o;
        }
    }
}

// ---------------------------------------------------------------------------
// flash8: all heads, grid (64 qb of 64 rows, 8 h).  Q read from d_out, Zcat
// written back to the same region.  K transposed in LDS (b128 reads), V bf16
// in LDS, P wave-private (shuffle softmax, no barrier).  2 barriers/kb.
// ---------------------------------------------------------------------------
__global__ __launch_bounds__(256) void flash8_kernel(const float* __restrict__ Kws,
                                                     const u16* __restrict__ Vws,
                                                     float* __restrict__ QZ) {
    const int qb = blockIdx.x;
    const int h = blockIdx.y;
    const float* Kh = Kws + (long)h * 4096 * 64;
    const u16* Vh = Vws + (long)h * 4096 * 64;

    __shared__ float sQ[64][68];
    __shared__ float sKt[64][68];     // [d][kcol]
    __shared__ u16 sV[64][72];        // [k][col] bf16
    __shared__ float sP[4][16][68];   // [wave][r_local][k]

    const int t = threadIdx.x;
    const int tx = t & 15, ty = t >> 4;
    const int w = t >> 6;
    const int lrow = (ty & 3) << 2;

    // Q tile load (coalesced)
    #pragma unroll
    for (int c = 0; c < 4; ++c) {
        int u = t + 256 * c;
        int r = u >> 4, cq = (u & 15) << 2;
        *(float4*)&sQ[r][cq] =
            *(const float4*)(QZ + (long)(qb * 64 + r) * 512 + h * 64 + cq);
    }

    float m_i[4], l_i[4], acc[4][4];
    #pragma unroll
    for (int i = 0; i < 4; ++i) {
        m_i[i] = -INFINITY; l_i[i] = 0.0f;
        #pragma unroll
        for (int j = 0; j < 4; ++j) acc[i][j] = 0.0f;
    }
    __syncthreads();

    for (int kb = 0; kb < 64; ++kb) {
        const int kr0 = kb * 64;
        // K staging, transposed: lane handles row (t&63), 4 col-chunks
        {
            const int r = t & 63;
            #pragma unroll
            for (int c = 0; c < 4; ++c) {
                const int cc = ((t >> 6) << 2) + (c << 4);
                float4 k4 = *(const float4*)(Kh + (long)(kr0 + r) * 64 + cc);
                sKt[cc + 0][r] = k4.x;
                sKt[cc + 1][r] = k4.y;
                sKt[cc + 2][r] = k4.z;
                sKt[cc + 3][r] = k4.w;
            }
        }
        // V staging bf16 (coalesced uint4)
        #pragma unroll
        for (int c = 0; c < 2; ++c) {
            int u = t + 256 * c;
            int r = u >> 3, cv = (u & 7) << 3;
            *(uint4*)&sV[r][cv] =
                *(const uint4*)(Vh + (long)(kr0 + r) * 64 + cv);
        }
        __syncthreads();

        // S = Q K^T / 8  (4x4 per thread)
        float s[4][4] = {};
        for (int d = 0; d < 64; ++d) {
            float a0 = sQ[(ty << 2) + 0][d];
            float a1 = sQ[(ty << 2) + 1][d];
            float a2 = sQ[(ty << 2) + 2][d];
            float a3 = sQ[(ty << 2) + 3][d];
            float4 k4 = *(const float4*)&sKt[d][tx << 2];
            s[0][0] = fmaf(a0, k4.x, s[0][0]); s[0][1] = fmaf(a0, k4.y, s[0][1]);
            s[0][2] = fmaf(a0, k4.z, s[0][2]); s[0][3] = fmaf(a0, k4.w, s[0][3]);
            s[1][0] = fmaf(a1, k4.x, s[1][0]); s[1][1] = fmaf(a1, k4.y, s[1][1]);
            s[1][2] = fmaf(a1, k4.z, s[1][2]); s[1][3] = fmaf(a1, k4.w, s[1][3]);
            s[2][0] = fmaf(a2, k4.x, s[2][0]); s[2][1] = fmaf(a2, k4.y, s[2][1]);
            s[2][2] = fmaf(a2, k4.z, s[2][2]); s[2][3] = fmaf(a2, k4.w, s[2][3]);
            s[3][0] = fmaf(a3, k4.x, s[3][0]); s[3][1] = fmaf(a3, k4.y, s[3][1]);
            s[3][2] = fmaf(a3, k4.z, s[3][2]); s[3][3] = fmaf(a3, k4.w, s[3][3]);
        }

        // online softmax per row: intra-wave shuffle over the 16-lane group
        #pragma unroll
        for (int i = 0; i < 4; ++i) {
            float rm = -INFINITY;
            #pragma unroll
            for (int j = 0; j < 4; ++j) {
                s[i][j] *= 0.125f;
                rm = fmaxf(rm, s[i][j]);
            }
            rm = fmaxf(rm, __shfl_xor(rm, 1, 16));
            rm = fmaxf(rm, __shfl_xor(rm, 2, 16));
            rm = fmaxf(rm, __shfl_xor(rm, 4, 16));
            rm = fmaxf(rm, __shfl_xor(rm, 8, 16));
            const float nm = fmaxf(m_i[i], rm);
            const float al = __expf(m_i[i] - nm);   // first block: exp(-inf)=0
            float p0 = __expf(s[i][0] - nm), p1 = __expf(s[i][1] - nm);
            float p2 = __expf(s[i][2] - nm), p3 = __expf(s[i][3] - nm);
            float ps = p0 + p1 + p2 + p3;
            ps += __shfl_xor(ps, 1, 16);
            ps += __shfl_xor(ps, 2, 16);
            ps += __shfl_xor(ps, 4, 16);
            ps += __shfl_xor(ps, 8, 16);
            l_i[i] = l_i[i] * al + ps;
            m_i[i] = nm;
            #pragma unroll
            for (int j = 0; j < 4; ++j) acc[i][j] *= al;
            *(float4*)&sP[w][lrow + i][tx << 2] = make_float4(p0, p1, p2, p3);
        }

        // PV (P is wave-private: no barrier between write and read)
        for (int k = 0; k < 64; ++k) {
            ushort4 vb = *(const ushort4*)&sV[k][tx << 2];
            float v0 = us2f(vb.x), v1 = us2f(vb.y), v2 = us2f(vb.z), v3 = us2f(vb.w);
            float p0 = sP[w][lrow + 0][k];
            float p1 = sP[w][lrow + 1][k];
            float p2 = sP[w][lrow + 2][k];
            float p3 = sP[w][lrow + 3][k];
            acc[0][0] = fmaf(p0, v0, acc[0][0]); acc[0][1] = fmaf(p0, v1, acc[0][1]);
            acc[0][2] = fmaf(p0, v2, acc[0][2]); acc[0][3] = fmaf(p0, v3, acc[0][3]);
            acc[1][0] = fmaf(p1, v0, acc[1][0]); acc[1][1] = fmaf(p1, v1, acc[1][1]);
            acc[1][2] = fmaf(p1, v2, acc[1][2]); acc[1][3] = fmaf(p1, v3, acc[1][3]);
            acc[2][0] = fmaf(p2, v0, acc[2][0]); acc[2][1] = fmaf(p2, v1, acc[2][1]);
            acc[2][2] = fmaf(p2, v2, acc[2][2]); acc[2][3] = fmaf(p2, v3, acc[2][3]);
            acc[3][0] = fmaf(p3, v0, acc[3][0]); acc[3][1] = fmaf(p3, v1, acc[3][1]);
            acc[3][2] = fmaf(p3, v2, acc[3][2]); acc[3][3] = fmaf(p3, v3, acc[3][3]);
        }
        __syncthreads();
    }

    #pragma unroll
    for (int i = 0; i < 4; ++i) {
        const int row = qb * 64 + (ty << 2) + i;
        const float inv = 1.0f / l_i[i];
        *(float4*)(QZ + (long)row * 512 + h * 64 + (tx << 2)) =
            make_float4(acc[i][0] * inv, acc[i][1] * inv,
                        acc[i][2] * inv, acc[i][3] * inv);
    }
}

// ---------------------------------------------------------------------------
// wo: tmp = Zcat @ WO.  grid (8 nb, 64 mb).
// ---------------------------------------------------------------------------
__global__ __launch_bounds__(256) void wo_kernel(const float* __restrict__ A,
                                                 const float* __restrict__ B,
                                                 float* __restrict__ C) {
    __shared__ float sA[64][17];
    __shared__ float sB[16][68];
    const int t = threadIdx.x;
    const int tx = t & 15, ty = t >> 4;
    const int m0 = blockIdx.y * 64, n0 = blockIdx.x * 64;
    const int ar = t >> 2, ac = (t & 3) << 2;

    float acc[4][4] = {};
    for (int k0 = 0; k0 < 512; k0 += 16) {
        *(float4*)&sA[ar][ac] =
            *(const float4*)(A + (long)(m0 + ar) * 512 + k0 + ac);
        *(float4*)&sB[ty][tx << 2] =
            *(const float4*)(B + (long)(k0 + ty) * 512 + n0 + (tx << 2));
        __syncthreads();
        #pragma unroll
        for (int kk = 0; kk < 16; ++kk) {
            float a0 = sA[(ty << 2) + 0][kk];
            float a1 = sA[(ty << 2) + 1][kk];
            float a2 = sA[(ty << 2) + 2][kk];
            float a3 = sA[(ty << 2) + 3][kk];
            float4 b4 = *(const float4*)&sB[kk][tx << 2];
            acc[0][0] = fmaf(a0, b4.x, acc[0][0]); acc[0][1] = fmaf(a0, b4.y, acc[0][1]);
            acc[0][2] = fmaf(a0, b4.z, acc[0][2]); acc[0][3] = fmaf(a0, b4.w, acc[0][3]);
            acc[1][0] = fmaf(a1, b4.x, acc[1][0]); acc[1][1] = fmaf(a1, b4.y, acc[1][1]);
            acc[1][2] = fmaf(a1, b4.z, acc[1][2]); acc[1][3] = fmaf(a1, b4.w, acc[1][3]);
            acc[2][0] = fmaf(a2, b4.x, acc[2][0]); acc[2][1] = fmaf(a2, b4.y, acc[2][1]);
            acc[2][2] = fmaf(a2, b4.z, acc[2][2]); acc[2][3] = fmaf(a2, b4.w, acc[2][3]);
            acc[3][0] = fmaf(a3, b4.x, acc[3][0]); acc[3][1] = fmaf(a3, b4.y, acc[3][1]);
            acc[3][2] = fmaf(a3, b4.z, acc[3][2]); acc[3][3] = fmaf(a3, b4.w, acc[3][3]);
        }
        __syncthreads();
    }
    #pragma unroll
    for (int i = 0; i < 4; ++i)
        *(float4*)(C + (long)(m0 + (ty << 2) + i) * 512 + n0 + (tx << 2)) =
            make_float4(acc[i][0], acc[i][1], acc[i][2], acc[i][3]);
}

// ---------------------------------------------------------------------------
// ln1: Z1 = LN(tmp + E + posenc)*g + be -> d_out (in place over Zcat).
// ---------------------------------------------------------------------------
__global__ __launch_bounds__(256) void ln1_kernel(const float* __restrict__ tmp,
                                                  const float* __restrict__ E,
                                                  const float* __restrict__ g,
                                                  const float* __restrict__ be,
                                                  float* __restrict__ out) {
    const int r = blockIdx.x, t = threadIdx.x;
    const long base = (long)r * 512;
    __shared__ float red[256];

    float v0 = tmp[base + t] + (float)((double)E[base + t] + posenc_d(r, t));
    float v1 = tmp[base + t + 256] +
               (float)((double)E[base + t + 256] + posenc_d(r, t + 256));

    red[t] = v0 + v1; __syncthreads();
    for (int s2 = 128; s2 > 0; s2 >>= 1) {
        if (t < s2) red[t] += red[t + s2];
        __syncthreads();
    }
    const float mean = red[0] * (1.0f / 512.0f);
    __syncthreads();
    float d0 = v0 - mean, d1 = v1 - mean;
    red[t] = d0 * d0 + d1 * d1; __syncthreads();
    for (int s2 = 128; s2 > 0; s2 >>= 1) {
        if (t < s2) red[t] += red[t + s2];
        __syncthreads();
    }
    const float rs = rsqrtf(red[0] * (1.0f / 512.0f) + LN_EPS);
    out[base + t] = d0 * rs * g[t] + be[t];
    out[base + t + 256] = d1 * rs * g[t + 256] + be[t + 256];
}

// ---------------------------------------------------------------------------
// ffn1: Hff(bf16) = relu(Z1c @ W1 + b1).  grid (32 nb, 32 mb) per 2048 rows.
// ---------------------------------------------------------------------------
__global__ __launch_bounds__(256) void ffn1_kernel(const float* __restrict__ A,
                                                   const float* __restrict__ W1,
                                                   const float* __restrict__ b1,
                                                   u16* __restrict__ C) {
    __shared__ float sA[64][17];
    __shared__ float sB[16][68];
    const int t = threadIdx.x;
    const int tx = t & 15, ty = t >> 4;
    const int m0 = blockIdx.y * 64, n0 = blockIdx.x * 64;
    const int ar = t >> 2, ac = (t & 3) << 2;

    float acc[4][4] = {};
    for (int k0 = 0; k0 < 512; k0 += 16) {
        *(float4*)&sA[ar][ac] =
            *(const float4*)(A + (long)(m0 + ar) * 512 + k0 + ac);
        *(float4*)&sB[ty][tx << 2] =
            *(const float4*)(W1 + (long)(k0 + ty) * 2048 + n0 + (tx << 2));
        __syncthreads();
        #pragma unroll
        for (int kk = 0; kk < 16; ++kk) {
            float a0 = sA[(ty << 2) + 0][kk];
            float a1 = sA[(ty << 2) + 1][kk];
            float a2 = sA[(ty << 2) + 2][kk];
            float a3 = sA[(ty << 2) + 3][kk];
            float4 b4 = *(const float4*)&sB[kk][tx << 2];
            acc[0][0] = fmaf(a0, b4.x, acc[0][0]); acc[0][1] = fmaf(a0, b4.y, acc[0][1]);
            acc[0][2] = fmaf(a0, b4.z, acc[0][2]); acc[0][3] = fmaf(a0, b4.w, acc[0][3]);
            acc[1][0] = fmaf(a1, b4.x, acc[1][0]); acc[1][1] = fmaf(a1, b4.y, acc[1][1]);
            acc[1][2] = fmaf(a1, b4.z, acc[1][2]); acc[1][3] = fmaf(a1, b4.w, acc[1][3]);
            acc[2][0] = fmaf(a2, b4.x, acc[2][0]); acc[2][1] = fmaf(a2, b4.y, acc[2][1]);
            acc[2][2] = fmaf(a2, b4.z, acc[2][2]); acc[2][3] = fmaf(a2, b4.w, acc[2][3]);
            acc[3][0] = fmaf(a3, b4.x, acc[3][0]); acc[3][1] = fmaf(a3, b4.y, acc[3][1]);
            acc[3][2] = fmaf(a3, b4.z, acc[3][2]); acc[3][3] = fmaf(a3, b4.w, acc[3][3]);
        }
        __syncthreads();
    }
    #pragma unroll
    for (int i = 0; i < 4; ++i) {
        const int cn = n0 + (tx << 2);
        ushort4 o;
        o.x = f2us(fmaxf(acc[i][0] + b1[cn + 0], 0.0f));
        o.y = f2us(fmaxf(acc[i][1] + b1[cn + 1], 0.0f));
        o.z = f2us(fmaxf(acc[i][2] + b1[cn + 2], 0.0f));
        o.w = f2us(fmaxf(acc[i][3] + b1[cn + 3], 0.0f));
        *(ushort4*)(C + (long)(m0 + (ty << 2) + i) * 2048 + cn) = o;
    }
}

// ---------------------------------------------------------------------------
// ffn2: U = Hff(bf16) @ W2 + b2 -> f32.  grid (8 nb, 32 mb) per chunk.
// ---------------------------------------------------------------------------
__global__ __launch_bounds__(256) void ffn2_kernel(const u16* __restrict__ A,
                                                   const float* __restrict__ W2,
                                                   const float* __restrict__ b2,
                                                   float* __restrict__ U) {
    __shared__ float sA[64][17];
    __shared__ float sB[16][68];
    const int t = threadIdx.x;
    const int tx = t & 15, ty = t >> 4;
    const int m0 = blockIdx.y * 64, n0 = blockIdx.x * 64;
    const int ar = t >> 2, ac = (t & 3) << 2;

    float acc[4][4] = {};
    for (int k0 = 0; k0 < 2048; k0 += 16) {
        ushort4 av = *(const ushort4*)(A + (long)(m0 + ar) * 2048 + k0 + ac);
        sA[ar][ac + 0] = us2f(av.x); sA[ar][ac + 1] = us2f(av.y);
        sA[ar][ac + 2] = us2f(av.z); sA[ar][ac + 3] = us2f(av.w);
        *(float4*)&sB[ty][tx << 2] =
            *(const float4*)(W2 + (long)(k0 + ty) * 512 + n0 + (tx << 2));
        __syncthreads();
        #pragma unroll
        for (int kk = 0; kk < 16; ++kk) {
            float a0 = sA[(ty << 2) + 0][kk];
            float a1 = sA[(ty << 2) + 1][kk];
            float a2 = sA[(ty << 2) + 2][kk];
            float a3 = sA[(ty << 2) + 3][kk];
            float4 b4 = *(const float4*)&sB[kk][tx << 2];
            acc[0][0] = fmaf(a0, b4.x, acc[0][0]); acc[0][1] = fmaf(a0, b4.y, acc[0][1]);
            acc[0][2] = fmaf(a0, b4.z, acc[0][2]); acc[0][3] = fmaf(a0, b4.w, acc[0][3]);
            acc[1][0] = fmaf(a1, b4.x, acc[1][0]); acc[1][1] = fmaf(a1, b4.y, acc[1][1]);
            acc[1][2] = fmaf(a1, b4.z, acc[1][2]); acc[1][3] = fmaf(a1, b4.w, acc[1][3]);
            acc[2][0] = fmaf(a2, b4.x, acc[2][0]); acc[2][1] = fmaf(a2, b4.y, acc[2][1]);
            acc[2][2] = fmaf(a2, b4.z, acc[2][2]); acc[2][3] = fmaf(a2, b4.w, acc[2][3]);
            acc[3][0] = fmaf(a3, b4.x, acc[3][0]); acc[3][1] = fmaf(a3, b4.y, acc[3][1]);
            acc[3][2] = fmaf(a3, b4.z, acc[3][2]); acc[3][3] = fmaf(a3, b4.w, acc[3][3]);
        }
        __syncthreads();
    }
    #pragma unroll
    for (int i = 0; i < 4; ++i) {
        const int cn = n0 + (tx << 2);
        *(float4*)(U + (long)(m0 + (ty << 2) + i) * 512 + cn) =
            make_float4(acc[i][0] + b2[cn + 0], acc[i][1] + b2[cn + 1],
                        acc[i][2] + b2[cn + 2], acc[i][3] + b2[cn + 3]);
    }
}

// ---------------------------------------------------------------------------
// ln2: out = LN(U + Z1)*g + be (in place over Z1 rows).
// ---------------------------------------------------------------------------
__global__ __launch_bounds__(256) void ln2_kernel(const float* __restrict__ U,
                                                  const float* __restrict__ Z1,
                                                  const float* __restrict__ g,
                                                  const float* __restrict__ be,
                                                  float* __restrict__ out) {
    const int r = blockIdx.x, t = threadIdx.x;
    const long base = (long)r * 512;
    __shared__ float red[256];

    float v0 = U[base + t] + Z1[base + t];
    float v1 = U[base + t + 256] + Z1[base + t + 256];

    red[t] = v0 + v1; __syncthreads();
    for (int s2 = 128; s2 > 0; s2 >>= 1) {
        if (t < s2) red[t] += red[t + s2];
        __syncthreads();
    }
    const float mean = red[0] * (1.0f / 512.0f);
    __syncthreads();
    float d0 = v0 - mean, d1 = v1 - mean;
    red[t] = d0 * d0 + d1 * d1; __syncthreads();
    for (int s2 = 128; s2 > 0; s2 >>= 1) {
        if (t < s2) red[t] += red[t + s2];
        __syncthreads();
    }
    const float rs = rsqrtf(red[0] * (1.0f / 512.0f) + LN_EPS);
    out[base + t] = d0 * rs * g[t] + be[t];
    out[base + t + 256] = d1 * rs * g[t + 256] + be[t + 256];
}

// ---------------------------------------------------------------------------
// ws (max 12 MB; proven budget >= 14 MB):
//   attention: K f32 @0 (8 MB) | V bf16 @8MB (4 MB)
//   post-attn: tmp f32 @0 (8 MB)
//   FFN chunk: Hff bf16 @0 (8 MB) | U f32 @8MB (4 MB)
// d_out: Qcat -> Zcat -> Z1 -> final out (race-free phase overwrites).
// ---------------------------------------------------------------------------
extern "C" void kernel_launch(void* const* d_in, const int* in_sizes, int n_in,
                              void* d_out, int out_size, void* d_ws, size_t ws_size,
                              hipStream_t stream) {
    float* outf = (float*)d_out;

    static const int exp_sizes[13] = {2097152, 262144, 262144, 262144, 262144,
                                      1048576, 2048, 1048576, 512, 512, 512,
                                      512, 512};
    bool ok = (n_in == 13) && (out_size == 2097152) &&
              (ws_size >= (14ull << 20));
    if (ok) for (int i = 0; i < 13; ++i) if (in_sizes[i] != exp_sizes[i]) ok = false;
    if (!ok) { sentinel_kernel<<<16, 256, 0, stream>>>(outf, 1000.0f); return; }

    const float* E   = (const float*)d_in[0];
    const float* Wq  = (const float*)d_in[1];
    const float* Wk  = (const float*)d_in[2];
    const float* Wv  = (const float*)d_in[3];
    const float* WO  = (const float*)d_in[4];
    const float* W1  = (const float*)d_in[5];
    const float* b1  = (const float*)d_in[6];
    const float* W2  = (const float*)d_in[7];
    const float* b2  = (const float*)d_in[8];
    const float* g1  = (const float*)d_in[9];
    const float* be1 = (const float*)d_in[10];
    const float* g2  = (const float*)d_in[11];
    const float* be2 = (const float*)d_in[12];

    char* base = (char*)d_ws;
    float* Kws = (float*)base;                 // 8 MB
    u16*   Vws = (u16*)(base + (8l << 20));    // 4 MB
    float* tmp = (float*)base;                 // 8 MB (K dead)
    u16*   Hff = (u16*)base;                   // 8 MB (tmp dead)
    float* U   = (float*)(base + (8l << 20));  // 4 MB (V dead)

    // 1. QKV for all heads (posenc inline); Q -> d_out (Qcat)
    qkv8_kernel<<<dim3(64, 24), 256, 0, stream>>>(E, Wq, Wk, Wv, outf, Kws, Vws);

    // 2. flash attention, all heads; Zcat overwrites Qcat in d_out
    flash8_kernel<<<dim3(64, 8), 256, 0, stream>>>(Kws, Vws, outf);

    // 3. tmp = Zcat @ WO ; Z1 = LN(tmp + x) in place in d_out
    wo_kernel<<<dim3(8, 64), 256, 0, stream>>>(outf, WO, tmp);
    ln1_kernel<<<4096, 256, 0, stream>>>(tmp, E, g1, be1, outf);

    // 4. FFN in 2 chunks of 2048 rows; final out in place in d_out
    for (int c = 0; c < 2; ++c) {
        float* Z1c = outf + (long)c * 2048 * 512;
        ffn1_kernel<<<dim3(32, 32), 256, 0, stream>>>(Z1c, W1, b1, Hff);
        ffn2_kernel<<<dim3(8, 32), 256, 0, stream>>>(Hff, W2, b2, U);
        ln2_kernel<<<2048, 256, 0, stream>>>(U, Z1c, g2, be2, Z1c);
    }
}

// Round 12
// 888.711 us; speedup vs baseline: 13.1910x; 1.3828x over previous
//
#include <hip/hip_runtime.h>
#include <hip/hip_bf16.h>
#include <cmath>

typedef unsigned short u16;
typedef __attribute__((ext_vector_type(8))) short short8;
typedef __attribute__((ext_vector_type(4))) float float4v;
#define LN_EPS 1e-5f

__device__ __forceinline__ float us2f(u16 u) {
    return __uint_as_float(((unsigned int)u) << 16);
}
__device__ __forceinline__ u16 f2us(float f) {
    __hip_bfloat16 h = __float2bfloat16(f);
    return *(u16*)&h;
}

// posenc in f64 (the only f64 left: f32 sin(up to 4095 rad) errs 2.4e-4
// coherently into logits).
__device__ __forceinline__ double posenc_d(int s, int d) {
    double expo = (double)(d & ~1) * (1.0 / 512.0);
    double ang = (double)s * exp(-expo * 9.210340371976184);
    return (d & 1) ? cos(ang) : sin(ang);
}

__global__ __launch_bounds__(256) void sentinel_kernel(float* out, float v) {
    out[blockIdx.x * 256 + threadIdx.x] = v;
}

// ---------------------------------------------------------------------------
// qkv8: unchanged from round 11 (proven).
// ---------------------------------------------------------------------------
__global__ __launch_bounds__(256) void qkv8_kernel(const float* __restrict__ E,
                                                   const float* __restrict__ Wq,
                                                   const float* __restrict__ Wk,
                                                   const float* __restrict__ Wv,
                                                   float* __restrict__ Qcat,
                                                   float* __restrict__ Kws,
                                                   u16* __restrict__ Vws) {
    const int z = blockIdx.y;
    const int type = z >> 3, h = z & 7;
    const float* W = (type == 0 ? Wq : type == 1 ? Wk : Wv) + (long)h * 512 * 64;

    __shared__ float sA[64][17];
    __shared__ float sB[16][68];
    __shared__ double sFreq[512];

    const int t = threadIdx.x;
    const int tx = t & 15, ty = t >> 4;
    const int m0 = blockIdx.x * 64;
    const int ar = t >> 2, ac = (t & 3) << 2;

    sFreq[t] = exp(-((double)(t & ~1) * (1.0 / 512.0)) * 9.210340371976184);
    sFreq[t + 256] = exp(-((double)((t + 256) & ~1) * (1.0 / 512.0)) * 9.210340371976184);
    __syncthreads();

    float acc[4][4] = {};
    for (int k0 = 0; k0 < 512; k0 += 16) {
        float4 av = *(const float4*)(E + (long)(m0 + ar) * 512 + k0 + ac);
        float ax[4] = {av.x, av.y, av.z, av.w};
        #pragma unroll
        for (int u = 0; u < 4; ++u) {
            const int col = k0 + ac + u;
            double ang = (double)(m0 + ar) * sFreq[col];
            double pe = (col & 1) ? cos(ang) : sin(ang);
            sA[ar][ac + u] = (float)((double)ax[u] + pe);
        }
        *(float4*)&sB[ty][tx << 2] =
            *(const float4*)(W + (long)(k0 + ty) * 64 + (tx << 2));
        __syncthreads();
        #pragma unroll
        for (int kk = 0; kk < 16; ++kk) {
            float a0 = sA[(ty << 2) + 0][kk];
            float a1 = sA[(ty << 2) + 1][kk];
            float a2 = sA[(ty << 2) + 2][kk];
            float a3 = sA[(ty << 2) + 3][kk];
            float4 b4 = *(const float4*)&sB[kk][tx << 2];
            acc[0][0] = fmaf(a0, b4.x, acc[0][0]); acc[0][1] = fmaf(a0, b4.y, acc[0][1]);
            acc[0][2] = fmaf(a0, b4.z, acc[0][2]); acc[0][3] = fmaf(a0, b4.w, acc[0][3]);
            acc[1][0] = fmaf(a1, b4.x, acc[1][0]); acc[1][1] = fmaf(a1, b4.y, acc[1][1]);
            acc[1][2] = fmaf(a1, b4.z, acc[1][2]); acc[1][3] = fmaf(a1, b4.w, acc[1][3]);
            acc[2][0] = fmaf(a2, b4.x, acc[2][0]); acc[2][1] = fmaf(a2, b4.y, acc[2][1]);
            acc[2][2] = fmaf(a2, b4.z, acc[2][2]); acc[2][3] = fmaf(a2, b4.w, acc[2][3]);
            acc[3][0] = fmaf(a3, b4.x, acc[3][0]); acc[3][1] = fmaf(a3, b4.y, acc[3][1]);
            acc[3][2] = fmaf(a3, b4.z, acc[3][2]); acc[3][3] = fmaf(a3, b4.w, acc[3][3]);
        }
        __syncthreads();
    }

    #pragma unroll
    for (int i = 0; i < 4; ++i) {
        const int row = m0 + (ty << 2) + i;
        if (type == 0) {
            *(float4*)(Qcat + (long)row * 512 + h * 64 + (tx << 2)) =
                make_float4(acc[i][0], acc[i][1], acc[i][2], acc[i][3]);
        } else if (type == 1) {
            *(float4*)(Kws + (long)h * 4096 * 64 + (long)row * 64 + (tx << 2)) =
                make_float4(acc[i][0], acc[i][1], acc[i][2], acc[i][3]);
        } else {
            ushort4 o;
            o.x = f2us(acc[i][0]); o.y = f2us(acc[i][1]);
            o.z = f2us(acc[i][2]); o.w = f2us(acc[i][3]);
            *(ushort4*)(Vws + (long)h * 4096 * 64 + (long)row * 64 + (tx << 2)) = o;
        }
    }
}

// ---------------------------------------------------------------------------
// flash8 (MFMA): grid (64 qb, 8 h), 256 thr = 4 waves, 16 q-rows per wave.
// S = Qhi*Khi + Qhi*Klo + Qlo*Khi (split-f32 via bf16 MFMA, 0.125 folded
// into Q).  P in bf16 via wave-private LDS (D-layout -> A-layout).  O in
// MFMA C-layout f32 regs.  2 barriers per kb.
// ---------------------------------------------------------------------------
__global__ __launch_bounds__(256) void flash8_kernel(const float* __restrict__ Kws,
                                                     const u16* __restrict__ Vws,
                                                     float* __restrict__ QZ) {
    const int qb = blockIdx.x, h = blockIdx.y;
    const float* Kg = Kws + (long)h * 4096 * 64;
    const u16* Vg = Vws + (long)h * 4096 * 64;

    __shared__ u16 sQh[64][72], sQl[64][72];
    __shared__ u16 sKh[64][72], sKl[64][72];
    __shared__ u16 sVt[64][72];       // [n][k] (transposed V tile)
    __shared__ u16 sP[4][16][72];     // wave-private P

    const int t = threadIdx.x;
    const int w = t >> 6;
    const int l = t & 63;
    const int quad = l >> 4;
    const int l16 = l & 15;
    const int mw = w * 16;

    // stage Q (x0.125, split hi/lo)
    {
        const int row = t >> 2, cc = (t & 3) << 4;
        #pragma unroll
        for (int u = 0; u < 4; ++u) {
            float4 q4 = *(const float4*)(QZ + (long)(qb * 64 + row) * 512 +
                                         h * 64 + cc + 4 * u);
            float qv[4] = {q4.x * 0.125f, q4.y * 0.125f,
                           q4.z * 0.125f, q4.w * 0.125f};
            ushort4 hh, ll;
            u16* hp = (u16*)&hh; u16* lp = (u16*)&ll;
            #pragma unroll
            for (int i = 0; i < 4; ++i) {
                u16 hi = f2us(qv[i]);
                hp[i] = hi;
                lp[i] = f2us(qv[i] - us2f(hi));
            }
            *(ushort4*)&sQh[row][cc + 4 * u] = hh;
            *(ushort4*)&sQl[row][cc + 4 * u] = ll;
        }
    }

    float m_i[4], l_i[4];
    float4v acc[4];
    #pragma unroll
    for (int r = 0; r < 4; ++r) { m_i[r] = -INFINITY; l_i[r] = 0.0f; }
    #pragma unroll
    for (int nt = 0; nt < 4; ++nt) acc[nt] = (float4v){0.f, 0.f, 0.f, 0.f};
    __syncthreads();

    for (int kb = 0; kb < 64; ++kb) {
        const int kr0 = kb * 64;
        // stage K hi/lo  (row-major [n][d], B-frag friendly)
        {
            const int row = t >> 2, cc = (t & 3) << 4;
            #pragma unroll
            for (int u = 0; u < 4; ++u) {
                float4 k4 = *(const float4*)(Kg + (long)(kr0 + row) * 64 + cc + 4 * u);
                float kv[4] = {k4.x, k4.y, k4.z, k4.w};
                ushort4 hh, ll;
                u16* hp = (u16*)&hh; u16* lp = (u16*)&ll;
                #pragma unroll
                for (int i = 0; i < 4; ++i) {
                    u16 hi = f2us(kv[i]);
                    hp[i] = hi;
                    lp[i] = f2us(kv[i] - us2f(hi));
                }
                *(ushort4*)&sKh[row][cc + 4 * u] = hh;
                *(ushort4*)&sKl[row][cc + 4 * u] = ll;
            }
        }
        // stage V transposed: sVt[n][k]
        {
            const int krow = t >> 2, nc = (t & 3) << 4;
            #pragma unroll
            for (int u = 0; u < 2; ++u) {
                uint4 vv = *(const uint4*)(Vg + (long)(kr0 + krow) * 64 + nc + 8 * u);
                const unsigned int wd[4] = {vv.x, vv.y, vv.z, vv.w};
                #pragma unroll
                for (int i = 0; i < 4; ++i) {
                    sVt[nc + 8 * u + 2 * i + 0][krow] = (u16)(wd[i] & 0xffff);
                    sVt[nc + 8 * u + 2 * i + 1][krow] = (u16)(wd[i] >> 16);
                }
            }
        }
        __syncthreads();

        // S tiles (4 x float4 per lane = 16 rows x 64 cols per wave)
        float4v s[4];
        #pragma unroll
        for (int nt = 0; nt < 4; ++nt) s[nt] = (float4v){0.f, 0.f, 0.f, 0.f};
        #pragma unroll
        for (int kc = 0; kc < 2; ++kc) {
            short8 aQh = *(const short8*)&sQh[mw + l16][kc * 32 + quad * 8];
            short8 aQl = *(const short8*)&sQl[mw + l16][kc * 32 + quad * 8];
            #pragma unroll
            for (int nt = 0; nt < 4; ++nt) {
                short8 bKh = *(const short8*)&sKh[nt * 16 + l16][kc * 32 + quad * 8];
                short8 bKl = *(const short8*)&sKl[nt * 16 + l16][kc * 32 + quad * 8];
                s[nt] = __builtin_amdgcn_mfma_f32_16x16x32_bf16(aQh, bKh, s[nt], 0, 0, 0);
                s[nt] = __builtin_amdgcn_mfma_f32_16x16x32_bf16(aQh, bKl, s[nt], 0, 0, 0);
                s[nt] = __builtin_amdgcn_mfma_f32_16x16x32_bf16(aQl, bKh, s[nt], 0, 0, 0);
            }
        }

        // online softmax, rows quad*4+r, cols across {nt, l16}
        #pragma unroll
        for (int r = 0; r < 4; ++r) {
            float rm = fmaxf(fmaxf(s[0][r], s[1][r]), fmaxf(s[2][r], s[3][r]));
            rm = fmaxf(rm, __shfl_xor(rm, 1, 16));
            rm = fmaxf(rm, __shfl_xor(rm, 2, 16));
            rm = fmaxf(rm, __shfl_xor(rm, 4, 16));
            rm = fmaxf(rm, __shfl_xor(rm, 8, 16));
            const float nm = fmaxf(m_i[r], rm);
            const float al = __expf(m_i[r] - nm);   // first block: exp(-inf)=0
            float p0 = __expf(s[0][r] - nm);
            float p1 = __expf(s[1][r] - nm);
            float p2 = __expf(s[2][r] - nm);
            float p3 = __expf(s[3][r] - nm);
            float ps = p0 + p1 + p2 + p3;
            ps += __shfl_xor(ps, 1, 16);
            ps += __shfl_xor(ps, 2, 16);
            ps += __shfl_xor(ps, 4, 16);
            ps += __shfl_xor(ps, 8, 16);
            l_i[r] = l_i[r] * al + ps;
            m_i[r] = nm;
            acc[0][r] *= al; acc[1][r] *= al;
            acc[2][r] *= al; acc[3][r] *= al;
            const int pr = quad * 4 + r;
            sP[w][pr][0 * 16 + l16] = f2us(p0);
            sP[w][pr][1 * 16 + l16] = f2us(p1);
            sP[w][pr][2 * 16 + l16] = f2us(p2);
            sP[w][pr][3 * 16 + l16] = f2us(p3);
        }

        // PV: O += P(16x64) * Vt  (sP wave-private; lgkmcnt handled by compiler)
        #pragma unroll
        for (int kc = 0; kc < 2; ++kc) {
            short8 aP = *(const short8*)&sP[w][l16][kc * 32 + quad * 8];
            #pragma unroll
            for (int nt = 0; nt < 4; ++nt) {
                short8 bV = *(const short8*)&sVt[nt * 16 + l16][kc * 32 + quad * 8];
                acc[nt] = __builtin_amdgcn_mfma_f32_16x16x32_bf16(aP, bV, acc[nt], 0, 0, 0);
            }
        }
        __syncthreads();
    }

    // write O (C-layout scatter; 64B-grouped dword stores)
    #pragma unroll
    for (int r = 0; r < 4; ++r) {
        const float inv = 1.0f / l_i[r];
        const int row = qb * 64 + mw + quad * 4 + r;
        #pragma unroll
        for (int nt = 0; nt < 4; ++nt)
            QZ[(long)row * 512 + h * 64 + nt * 16 + l16] = acc[nt][r] * inv;
    }
}

// ---------------------------------------------------------------------------
// wo / ln1 / ffn1 / ffn2 / ln2: unchanged from round 11 (proven).
// ---------------------------------------------------------------------------
__global__ __launch_bounds__(256) void wo_kernel(const float* __restrict__ A,
                                                 const float* __restrict__ B,
                                                 float* __restrict__ C) {
    __shared__ float sA[64][17];
    __shared__ float sB[16][68];
    const int t = threadIdx.x;
    const int tx = t & 15, ty = t >> 4;
    const int m0 = blockIdx.y * 64, n0 = blockIdx.x * 64;
    const int ar = t >> 2, ac = (t & 3) << 2;

    float acc[4][4] = {};
    for (int k0 = 0; k0 < 512; k0 += 16) {
        *(float4*)&sA[ar][ac] =
            *(const float4*)(A + (long)(m0 + ar) * 512 + k0 + ac);
        *(float4*)&sB[ty][tx << 2] =
            *(const float4*)(B + (long)(k0 + ty) * 512 + n0 + (tx << 2));
        __syncthreads();
        #pragma unroll
        for (int kk = 0; kk < 16; ++kk) {
            float a0 = sA[(ty << 2) + 0][kk];
            float a1 = sA[(ty << 2) + 1][kk];
            float a2 = sA[(ty << 2) + 2][kk];
            float a3 = sA[(ty << 2) + 3][kk];
            float4 b4 = *(const float4*)&sB[kk][tx << 2];
            acc[0][0] = fmaf(a0, b4.x, acc[0][0]); acc[0][1] = fmaf(a0, b4.y, acc[0][1]);
            acc[0][2] = fmaf(a0, b4.z, acc[0][2]); acc[0][3] = fmaf(a0, b4.w, acc[0][3]);
            acc[1][0] = fmaf(a1, b4.x, acc[1][0]); acc[1][1] = fmaf(a1, b4.y, acc[1][1]);
            acc[1][2] = fmaf(a1, b4.z, acc[1][2]); acc[1][3] = fmaf(a1, b4.w, acc[1][3]);
            acc[2][0] = fmaf(a2, b4.x, acc[2][0]); acc[2][1] = fmaf(a2, b4.y, acc[2][1]);
            acc[2][2] = fmaf(a2, b4.z, acc[2][2]); acc[2][3] = fmaf(a2, b4.w, acc[2][3]);
            acc[3][0] = fmaf(a3, b4.x, acc[3][0]); acc[3][1] = fmaf(a3, b4.y, acc[3][1]);
            acc[3][2] = fmaf(a3, b4.z, acc[3][2]); acc[3][3] = fmaf(a3, b4.w, acc[3][3]);
        }
        __syncthreads();
    }
    #pragma unroll
    for (int i = 0; i < 4; ++i)
        *(float4*)(C + (long)(m0 + (ty << 2) + i) * 512 + n0 + (tx << 2)) =
            make_float4(acc[i][0], acc[i][1], acc[i][2], acc[i][3]);
}

__global__ __launch_bounds__(256) void ln1_kernel(const float* __restrict__ tmp,
                                                  const float* __restrict__ E,
                                                  const float* __restrict__ g,
                                                  const float* __restrict__ be,
                                                  float* __restrict__ out) {
    const int r = blockIdx.x, t = threadIdx.x;
    const long base = (long)r * 512;
    __shared__ float red[256];

    float v0 = tmp[base + t] + (float)((double)E[base + t] + posenc_d(r, t));
    float v1 = tmp[base + t + 256] +
               (float)((double)E[base + t + 256] + posenc_d(r, t + 256));

    red[t] = v0 + v1; __syncthreads();
    for (int s2 = 128; s2 > 0; s2 >>= 1) {
        if (t < s2) red[t] += red[t + s2];
        __syncthreads();
    }
    const float mean = red[0] * (1.0f / 512.0f);
    __syncthreads();
    float d0 = v0 - mean, d1 = v1 - mean;
    red[t] = d0 * d0 + d1 * d1; __syncthreads();
    for (int s2 = 128; s2 > 0; s2 >>= 1) {
        if (t < s2) red[t] += red[t + s2];
        __syncthreads();
    }
    const float rs = rsqrtf(red[0] * (1.0f / 512.0f) + LN_EPS);
    out[base + t] = d0 * rs * g[t] + be[t];
    out[base + t + 256] = d1 * rs * g[t + 256] + be[t + 256];
}

__global__ __launch_bounds__(256) void ffn1_kernel(const float* __restrict__ A,
                                                   const float* __restrict__ W1,
                                                   const float* __restrict__ b1,
                                                   u16* __restrict__ C) {
    __shared__ float sA[64][17];
    __shared__ float sB[16][68];
    const int t = threadIdx.x;
    const int tx = t & 15, ty = t >> 4;
    const int m0 = blockIdx.y * 64, n0 = blockIdx.x * 64;
    const int ar = t >> 2, ac = (t & 3) << 2;

    float acc[4][4] = {};
    for (int k0 = 0; k0 < 512; k0 += 16) {
        *(float4*)&sA[ar][ac] =
            *(const float4*)(A + (long)(m0 + ar) * 512 + k0 + ac);
        *(float4*)&sB[ty][tx << 2] =
            *(const float4*)(W1 + (long)(k0 + ty) * 2048 + n0 + (tx << 2));
        __syncthreads();
        #pragma unroll
        for (int kk = 0; kk < 16; ++kk) {
            float a0 = sA[(ty << 2) + 0][kk];
            float a1 = sA[(ty << 2) + 1][kk];
            float a2 = sA[(ty << 2) + 2][kk];
            float a3 = sA[(ty << 2) + 3][kk];
            float4 b4 = *(const float4*)&sB[kk][tx << 2];
            acc[0][0] = fmaf(a0, b4.x, acc[0][0]); acc[0][1] = fmaf(a0, b4.y, acc[0][1]);
            acc[0][2] = fmaf(a0, b4.z, acc[0][2]); acc[0][3] = fmaf(a0, b4.w, acc[0][3]);
            acc[1][0] = fmaf(a1, b4.x, acc[1][0]); acc[1][1] = fmaf(a1, b4.y, acc[1][1]);
            acc[1][2] = fmaf(a1, b4.z, acc[1][2]); acc[1][3] = fmaf(a1, b4.w, acc[1][3]);
            acc[2][0] = fmaf(a2, b4.x, acc[2][0]); acc[2][1] = fmaf(a2, b4.y, acc[2][1]);
            acc[2][2] = fmaf(a2, b4.z, acc[2][2]); acc[2][3] = fmaf(a2, b4.w, acc[2][3]);
            acc[3][0] = fmaf(a3, b4.x, acc[3][0]); acc[3][1] = fmaf(a3, b4.y, acc[3][1]);
            acc[3][2] = fmaf(a3, b4.z, acc[3][2]); acc[3][3] = fmaf(a3, b4.w, acc[3][3]);
        }
        __syncthreads();
    }
    #pragma unroll
    for (int i = 0; i < 4; ++i) {
        const int cn = n0 + (tx << 2);
        ushort4 o;
        o.x = f2us(fmaxf(acc[i][0] + b1[cn + 0], 0.0f));
        o.y = f2us(fmaxf(acc[i][1] + b1[cn + 1], 0.0f));
        o.z = f2us(fmaxf(acc[i][2] + b1[cn + 2], 0.0f));
        o.w = f2us(fmaxf(acc[i][3] + b1[cn + 3], 0.0f));
        *(ushort4*)(C + (long)(m0 + (ty << 2) + i) * 2048 + cn) = o;
    }
}

__global__ __launch_bounds__(256) void ffn2_kernel(const u16* __restrict__ A,
                                                   const float* __restrict__ W2,
                                                   const float* __restrict__ b2,
                                                   float* __restrict__ U) {
    __shared__ float sA[64][17];
    __shared__ float sB[16][68];
    const int t = threadIdx.x;
    const int tx = t & 15, ty = t >> 4;
    const int m0 = blockIdx.y * 64, n0 = blockIdx.x * 64;
    const int ar = t >> 2, ac = (t & 3) << 2;

    float acc[4][4] = {};
    for (int k0 = 0; k0 < 2048; k0 += 16) {
        ushort4 av = *(const ushort4*)(A + (long)(m0 + ar) * 2048 + k0 + ac);
        sA[ar][ac + 0] = us2f(av.x); sA[ar][ac + 1] = us2f(av.y);
        sA[ar][ac + 2] = us2f(av.z); sA[ar][ac + 3] = us2f(av.w);
        *(float4*)&sB[ty][tx << 2] =
            *(const float4*)(W2 + (long)(k0 + ty) * 512 + n0 + (tx << 2));
        __syncthreads();
        #pragma unroll
        for (int kk = 0; kk < 16; ++kk) {
            float a0 = sA[(ty << 2) + 0][kk];
            float a1 = sA[(ty << 2) + 1][kk];
            float a2 = sA[(ty << 2) + 2][kk];
            float a3 = sA[(ty << 2) + 3][kk];
            float4 b4 = *(const float4*)&sB[kk][tx << 2];
            acc[0][0] = fmaf(a0, b4.x, acc[0][0]); acc[0][1] = fmaf(a0, b4.y, acc[0][1]);
            acc[0][2] = fmaf(a0, b4.z, acc[0][2]); acc[0][3] = fmaf(a0, b4.w, acc[0][3]);
            acc[1][0] = fmaf(a1, b4.x, acc[1][0]); acc[1][1] = fmaf(a1, b4.y, acc[1][1]);
            acc[1][2] = fmaf(a1, b4.z, acc[1][2]); acc[1][3] = fmaf(a1, b4.w, acc[1][3]);
            acc[2][0] = fmaf(a2, b4.x, acc[2][0]); acc[2][1] = fmaf(a2, b4.y, acc[2][1]);
            acc[2][2] = fmaf(a2, b4.z, acc[2][2]); acc[2][3] = fmaf(a2, b4.w, acc[2][3]);
            acc[3][0] = fmaf(a3, b4.x, acc[3][0]); acc[3][1] = fmaf(a3, b4.y, acc[3][1]);
            acc[3][2] = fmaf(a3, b4.z, acc[3][2]); acc[3][3] = fmaf(a3, b4.w, acc[3][3]);
        }
        __syncthreads();
    }
    #pragma unroll
    for (int i = 0; i < 4; ++i) {
        const int cn = n0 + (tx << 2);
        *(float4*)(U + (long)(m0 + (ty << 2) + i) * 512 + cn) =
            make_float4(acc[i][0] + b2[cn + 0], acc[i][1] + b2[cn + 1],
                        acc[i][2] + b2[cn + 2], acc[i][3] + b2[cn + 3]);
    }
}

__global__ __launch_bounds__(256) void ln2_kernel(const float* __restrict__ U,
                                                  const float* __restrict__ Z1,
                                                  const float* __restrict__ g,
                                                  const float* __restrict__ be,
                                                  float* __restrict__ out) {
    const int r = blockIdx.x, t = threadIdx.x;
    const long base = (long)r * 512;
    __shared__ float red[256];

    float v0 = U[base + t] + Z1[base + t];
    float v1 = U[base + t + 256] + Z1[base + t + 256];

    red[t] = v0 + v1; __syncthreads();
    for (int s2 = 128; s2 > 0; s2 >>= 1) {
        if (t < s2) red[t] += red[t + s2];
        __syncthreads();
    }
    const float mean = red[0] * (1.0f / 512.0f);
    __syncthreads();
    float d0 = v0 - mean, d1 = v1 - mean;
    red[t] = d0 * d0 + d1 * d1; __syncthreads();
    for (int s2 = 128; s2 > 0; s2 >>= 1) {
        if (t < s2) red[t] += red[t + s2];
        __syncthreads();
    }
    const float rs = rsqrtf(red[0] * (1.0f / 512.0f) + LN_EPS);
    out[base + t] = d0 * rs * g[t] + be[t];
    out[base + t + 256] = d1 * rs * g[t + 256] + be[t + 256];
}

// ---------------------------------------------------------------------------
// ws (max 12 MB; proven budget >= 14 MB):
//   attention: K f32 @0 (8 MB) | V bf16 @8MB (4 MB)
//   post-attn: tmp f32 @0 (8 MB)
//   FFN chunk: Hff bf16 @0 (8 MB) | U f32 @8MB (4 MB)
// d_out: Qcat -> Zcat -> Z1 -> final out (race-free phase overwrites).
// ---------------------------------------------------------------------------
extern "C" void kernel_launch(void* const* d_in, const int* in_sizes, int n_in,
                              void* d_out, int out_size, void* d_ws, size_t ws_size,
                              hipStream_t stream) {
    float* outf = (float*)d_out;

    static const int exp_sizes[13] = {2097152, 262144, 262144, 262144, 262144,
                                      1048576, 2048, 1048576, 512, 512, 512,
                                      512, 512};
    bool ok = (n_in == 13) && (out_size == 2097152) &&
              (ws_size >= (14ull << 20));
    if (ok) for (int i = 0; i < 13; ++i) if (in_sizes[i] != exp_sizes[i]) ok = false;
    if (!ok) { sentinel_kernel<<<16, 256, 0, stream>>>(outf, 1000.0f); return; }

    const float* E   = (const float*)d_in[0];
    const float* Wq  = (const float*)d_in[1];
    const float* Wk  = (const float*)d_in[2];
    const float* Wv  = (const float*)d_in[3];
    const float* WO  = (const float*)d_in[4];
    const float* W1  = (const float*)d_in[5];
    const float* b1  = (const float*)d_in[6];
    const float* W2  = (const float*)d_in[7];
    const float* b2  = (const float*)d_in[8];
    const float* g1  = (const float*)d_in[9];
    const float* be1 = (const float*)d_in[10];
    const float* g2  = (const float*)d_in[11];
    const float* be2 = (const float*)d_in[12];

    char* base = (char*)d_ws;
    float* Kws = (float*)base;                 // 8 MB
    u16*   Vws = (u16*)(base + (8l << 20));    // 4 MB
    float* tmp = (float*)base;                 // 8 MB (K dead)
    u16*   Hff = (u16*)base;                   // 8 MB (tmp dead)
    float* U   = (float*)(base + (8l << 20));  // 4 MB (V dead)

    qkv8_kernel<<<dim3(64, 24), 256, 0, stream>>>(E, Wq, Wk, Wv, outf, Kws, Vws);
    flash8_kernel<<<dim3(64, 8), 256, 0, stream>>>(Kws, Vws, outf);
    wo_kernel<<<dim3(8, 64), 256, 0, stream>>>(outf, WO, tmp);
    ln1_kernel<<<4096, 256, 0, stream>>>(tmp, E, g1, be1, outf);

    for (int c = 0; c < 2; ++c) {
        float* Z1c = outf + (long)c * 2048 * 512;
        ffn1_kernel<<<dim3(32, 32), 256, 0, stream>>>(Z1c, W1, b1, Hff);
        ffn2_kernel<<<dim3(8, 32), 256, 0, stream>>>(Hff, W2, b2, U);
        ln2_kernel<<<2048, 256, 0, stream>>>(U, Z1c, g2, be2, Z1c);
    }
}

// Round 13
// 672.949 us; speedup vs baseline: 17.4203x; 1.3206x over previous
//
#include <hip/hip_runtime.h>
#include <hip/hip_bf16.h>
#include <cmath>

typedef unsigned short u16;
typedef __attribute__((ext_vector_type(8))) short short8;
typedef __attribute__((ext_vector_type(4))) float float4v;
#define LN_EPS 1e-5f

__device__ __forceinline__ float us2f(u16 u) {
    return __uint_as_float(((unsigned int)u) << 16);
}
__device__ __forceinline__ u16 f2us(float f) {
    __hip_bfloat16 h = __float2bfloat16(f);
    return *(u16*)&h;
}

__device__ __forceinline__ double posenc_d(int s, int d) {
    double expo = (double)(d & ~1) * (1.0 / 512.0);
    double ang = (double)s * exp(-expo * 9.210340371976184);
    return (d & 1) ? cos(ang) : sin(ang);
}

__global__ __launch_bounds__(256) void sentinel_kernel(float* out, float v) {
    out[blockIdx.x * 256 + threadIdx.x] = v;
}

// ---------------------------------------------------------------------------
// qkv8: compute as round 12; epilogue writes Q f32 (d_out), K pre-split
// (Khi/Klo bf16), V pre-transposed into 64x64 B-frag tiles (bf16).
// grid (64 mb, 24 z).
// ---------------------------------------------------------------------------
__global__ __launch_bounds__(256) void qkv8_kernel(const float* __restrict__ E,
                                                   const float* __restrict__ Wq,
                                                   const float* __restrict__ Wk,
                                                   const float* __restrict__ Wv,
                                                   float* __restrict__ Qcat,
                                                   u16* __restrict__ Khi,
                                                   u16* __restrict__ Klo,
                                                   u16* __restrict__ Vt) {
    const int z = blockIdx.y;
    const int type = z >> 3, h = z & 7;
    const float* W = (type == 0 ? Wq : type == 1 ? Wk : Wv) + (long)h * 512 * 64;

    __shared__ float sA[64][17];
    __shared__ float sB[16][68];
    __shared__ double sFreq[512];

    const int t = threadIdx.x;
    const int tx = t & 15, ty = t >> 4;
    const int m0 = blockIdx.x * 64;
    const int ar = t >> 2, ac = (t & 3) << 2;

    sFreq[t] = exp(-((double)(t & ~1) * (1.0 / 512.0)) * 9.210340371976184);
    sFreq[t + 256] = exp(-((double)((t + 256) & ~1) * (1.0 / 512.0)) * 9.210340371976184);
    __syncthreads();

    float acc[4][4] = {};
    for (int k0 = 0; k0 < 512; k0 += 16) {
        float4 av = *(const float4*)(E + (long)(m0 + ar) * 512 + k0 + ac);
        float ax[4] = {av.x, av.y, av.z, av.w};
        #pragma unroll
        for (int u = 0; u < 4; ++u) {
            const int col = k0 + ac + u;
            double ang = (double)(m0 + ar) * sFreq[col];
            double pe = (col & 1) ? cos(ang) : sin(ang);
            sA[ar][ac + u] = (float)((double)ax[u] + pe);
        }
        *(float4*)&sB[ty][tx << 2] =
            *(const float4*)(W + (long)(k0 + ty) * 64 + (tx << 2));
        __syncthreads();
        #pragma unroll
        for (int kk = 0; kk < 16; ++kk) {
            float a0 = sA[(ty << 2) + 0][kk];
            float a1 = sA[(ty << 2) + 1][kk];
            float a2 = sA[(ty << 2) + 2][kk];
            float a3 = sA[(ty << 2) + 3][kk];
            float4 b4 = *(const float4*)&sB[kk][tx << 2];
            acc[0][0] = fmaf(a0, b4.x, acc[0][0]); acc[0][1] = fmaf(a0, b4.y, acc[0][1]);
            acc[0][2] = fmaf(a0, b4.z, acc[0][2]); acc[0][3] = fmaf(a0, b4.w, acc[0][3]);
            acc[1][0] = fmaf(a1, b4.x, acc[1][0]); acc[1][1] = fmaf(a1, b4.y, acc[1][1]);
            acc[1][2] = fmaf(a1, b4.z, acc[1][2]); acc[1][3] = fmaf(a1, b4.w, acc[1][3]);
            acc[2][0] = fmaf(a2, b4.x, acc[2][0]); acc[2][1] = fmaf(a2, b4.y, acc[2][1]);
            acc[2][2] = fmaf(a2, b4.z, acc[2][2]); acc[2][3] = fmaf(a2, b4.w, acc[2][3]);
            acc[3][0] = fmaf(a3, b4.x, acc[3][0]); acc[3][1] = fmaf(a3, b4.y, acc[3][1]);
            acc[3][2] = fmaf(a3, b4.z, acc[3][2]); acc[3][3] = fmaf(a3, b4.w, acc[3][3]);
        }
        __syncthreads();
    }

    if (type == 0) {
        #pragma unroll
        for (int i = 0; i < 4; ++i) {
            const int row = m0 + (ty << 2) + i;
            *(float4*)(Qcat + (long)row * 512 + h * 64 + (tx << 2)) =
                make_float4(acc[i][0], acc[i][1], acc[i][2], acc[i][3]);
        }
    } else if (type == 1) {
        #pragma unroll
        for (int i = 0; i < 4; ++i) {
            const int row = m0 + (ty << 2) + i;
            ushort4 hh, ll;
            u16* hp = (u16*)&hh; u16* lp = (u16*)&ll;
            #pragma unroll
            for (int j = 0; j < 4; ++j) {
                u16 hi = f2us(acc[i][j]);
                hp[j] = hi;
                lp[j] = f2us(acc[i][j] - us2f(hi));
            }
            const long off = ((long)h * 4096 + row) * 64 + (tx << 2);
            *(ushort4*)(Khi + off) = hh;
            *(ushort4*)(Klo + off) = ll;
        }
    } else {
        // transposed tile write: Vt[h][m0/64][col][rowlocal]
        #pragma unroll
        for (int j = 0; j < 4; ++j) {
            const int col = (tx << 2) + j;
            ushort4 o;
            o.x = f2us(acc[0][j]); o.y = f2us(acc[1][j]);
            o.z = f2us(acc[2][j]); o.w = f2us(acc[3][j]);
            *(ushort4*)(Vt + (((long)h * 64 + (m0 >> 6)) * 64 + col) * 64 +
                        (ty << 2)) = o;
        }
    }
}

// ---------------------------------------------------------------------------
// flash8 (MFMA): staging is now pure copies (K pre-split, V pre-transposed).
// grid (64 qb, 8 h).
// ---------------------------------------------------------------------------
__global__ __launch_bounds__(256) void flash8_kernel(const u16* __restrict__ Khi,
                                                     const u16* __restrict__ Klo,
                                                     const u16* __restrict__ Vt,
                                                     float* __restrict__ QZ) {
    const int qb = blockIdx.x, h = blockIdx.y;

    __shared__ u16 sQh[64][72], sQl[64][72];
    __shared__ u16 sKh[64][72], sKl[64][72];
    __shared__ u16 sVt[64][72];
    __shared__ u16 sP[4][16][72];

    const int t = threadIdx.x;
    const int w = t >> 6;
    const int l = t & 63;
    const int quad = l >> 4;
    const int l16 = l & 15;
    const int mw = w * 16;

    // stage Q (x0.125, split hi/lo) — once per block
    {
        const int row = t >> 2, cc = (t & 3) << 4;
        #pragma unroll
        for (int u = 0; u < 4; ++u) {
            float4 q4 = *(const float4*)(QZ + (long)(qb * 64 + row) * 512 +
                                         h * 64 + cc + 4 * u);
            float qv[4] = {q4.x * 0.125f, q4.y * 0.125f,
                           q4.z * 0.125f, q4.w * 0.125f};
            ushort4 hh, ll;
            u16* hp = (u16*)&hh; u16* lp = (u16*)&ll;
            #pragma unroll
            for (int i = 0; i < 4; ++i) {
                u16 hi = f2us(qv[i]);
                hp[i] = hi;
                lp[i] = f2us(qv[i] - us2f(hi));
            }
            *(ushort4*)&sQh[row][cc + 4 * u] = hh;
            *(ushort4*)&sQl[row][cc + 4 * u] = ll;
        }
    }

    float m_i[4], l_i[4];
    float4v acc[4];
    #pragma unroll
    for (int r = 0; r < 4; ++r) { m_i[r] = -INFINITY; l_i[r] = 0.0f; }
    #pragma unroll
    for (int nt = 0; nt < 4; ++nt) acc[nt] = (float4v){0.f, 0.f, 0.f, 0.f};
    __syncthreads();

    for (int kb = 0; kb < 64; ++kb) {
        const int kr0 = kb * 64;
        {
            const int r = t >> 2, cc = (t & 3) << 4;
            const long koff = ((long)h * 4096 + kr0 + r) * 64 + cc;
            *(uint4*)&sKh[r][cc]     = *(const uint4*)(Khi + koff);
            *(uint4*)&sKh[r][cc + 8] = *(const uint4*)(Khi + koff + 8);
            *(uint4*)&sKl[r][cc]     = *(const uint4*)(Klo + koff);
            *(uint4*)&sKl[r][cc + 8] = *(const uint4*)(Klo + koff + 8);
            const long voff = (((long)h * 64 + kb) * 64 + r) * 64 + cc;
            *(uint4*)&sVt[r][cc]     = *(const uint4*)(Vt + voff);
            *(uint4*)&sVt[r][cc + 8] = *(const uint4*)(Vt + voff + 8);
        }
        __syncthreads();

        float4v s[4];
        #pragma unroll
        for (int nt = 0; nt < 4; ++nt) s[nt] = (float4v){0.f, 0.f, 0.f, 0.f};
        #pragma unroll
        for (int kc = 0; kc < 2; ++kc) {
            short8 aQh = *(const short8*)&sQh[mw + l16][kc * 32 + quad * 8];
            short8 aQl = *(const short8*)&sQl[mw + l16][kc * 32 + quad * 8];
            #pragma unroll
            for (int nt = 0; nt < 4; ++nt) {
                short8 bKh = *(const short8*)&sKh[nt * 16 + l16][kc * 32 + quad * 8];
                short8 bKl = *(const short8*)&sKl[nt * 16 + l16][kc * 32 + quad * 8];
                s[nt] = __builtin_amdgcn_mfma_f32_16x16x32_bf16(aQh, bKh, s[nt], 0, 0, 0);
                s[nt] = __builtin_amdgcn_mfma_f32_16x16x32_bf16(aQh, bKl, s[nt], 0, 0, 0);
                s[nt] = __builtin_amdgcn_mfma_f32_16x16x32_bf16(aQl, bKh, s[nt], 0, 0, 0);
            }
        }

        #pragma unroll
        for (int r = 0; r < 4; ++r) {
            float rm = fmaxf(fmaxf(s[0][r], s[1][r]), fmaxf(s[2][r], s[3][r]));
            rm = fmaxf(rm, __shfl_xor(rm, 1, 16));
            rm = fmaxf(rm, __shfl_xor(rm, 2, 16));
            rm = fmaxf(rm, __shfl_xor(rm, 4, 16));
            rm = fmaxf(rm, __shfl_xor(rm, 8, 16));
            const float nm = fmaxf(m_i[r], rm);
            const float al = __expf(m_i[r] - nm);
            float p0 = __expf(s[0][r] - nm);
            float p1 = __expf(s[1][r] - nm);
            float p2 = __expf(s[2][r] - nm);
            float p3 = __expf(s[3][r] - nm);
            float ps = p0 + p1 + p2 + p3;
            ps += __shfl_xor(ps, 1, 16);
            ps += __shfl_xor(ps, 2, 16);
            ps += __shfl_xor(ps, 4, 16);
            ps += __shfl_xor(ps, 8, 16);
            l_i[r] = l_i[r] * al + ps;
            m_i[r] = nm;
            acc[0][r] *= al; acc[1][r] *= al;
            acc[2][r] *= al; acc[3][r] *= al;
            const int pr = quad * 4 + r;
            sP[w][pr][0 * 16 + l16] = f2us(p0);
            sP[w][pr][1 * 16 + l16] = f2us(p1);
            sP[w][pr][2 * 16 + l16] = f2us(p2);
            sP[w][pr][3 * 16 + l16] = f2us(p3);
        }

        #pragma unroll
        for (int kc = 0; kc < 2; ++kc) {
            short8 aP = *(const short8*)&sP[w][l16][kc * 32 + quad * 8];
            #pragma unroll
            for (int nt = 0; nt < 4; ++nt) {
                short8 bV = *(const short8*)&sVt[nt * 16 + l16][kc * 32 + quad * 8];
                acc[nt] = __builtin_amdgcn_mfma_f32_16x16x32_bf16(aP, bV, acc[nt], 0, 0, 0);
            }
        }
        __syncthreads();
    }

    #pragma unroll
    for (int r = 0; r < 4; ++r) {
        const float inv = 1.0f / l_i[r];
        const int row = qb * 64 + mw + quad * 4 + r;
        #pragma unroll
        for (int nt = 0; nt < 4; ++nt)
            QZ[(long)row * 512 + h * 64 + nt * 16 + l16] = acc[nt][r] * inv;
    }
}

// ---------------------------------------------------------------------------
// wo: tmp = Zcat @ WO (f32, unchanged).  grid (8 nb, 64 mb).
// ---------------------------------------------------------------------------
__global__ __launch_bounds__(256) void wo_kernel(const float* __restrict__ A,
                                                 const float* __restrict__ B,
                                                 float* __restrict__ C) {
    __shared__ float sA[64][17];
    __shared__ float sB[16][68];
    const int t = threadIdx.x;
    const int tx = t & 15, ty = t >> 4;
    const int m0 = blockIdx.y * 64, n0 = blockIdx.x * 64;
    const int ar = t >> 2, ac = (t & 3) << 2;

    float acc[4][4] = {};
    for (int k0 = 0; k0 < 512; k0 += 16) {
        *(float4*)&sA[ar][ac] =
            *(const float4*)(A + (long)(m0 + ar) * 512 + k0 + ac);
        *(float4*)&sB[ty][tx << 2] =
            *(const float4*)(B + (long)(k0 + ty) * 512 + n0 + (tx << 2));
        __syncthreads();
        #pragma unroll
        for (int kk = 0; kk < 16; ++kk) {
            float a0 = sA[(ty << 2) + 0][kk];
            float a1 = sA[(ty << 2) + 1][kk];
            float a2 = sA[(ty << 2) + 2][kk];
            float a3 = sA[(ty << 2) + 3][kk];
            float4 b4 = *(const float4*)&sB[kk][tx << 2];
            acc[0][0] = fmaf(a0, b4.x, acc[0][0]); acc[0][1] = fmaf(a0, b4.y, acc[0][1]);
            acc[0][2] = fmaf(a0, b4.z, acc[0][2]); acc[0][3] = fmaf(a0, b4.w, acc[0][3]);
            acc[1][0] = fmaf(a1, b4.x, acc[1][0]); acc[1][1] = fmaf(a1, b4.y, acc[1][1]);
            acc[1][2] = fmaf(a1, b4.z, acc[1][2]); acc[1][3] = fmaf(a1, b4.w, acc[1][3]);
            acc[2][0] = fmaf(a2, b4.x, acc[2][0]); acc[2][1] = fmaf(a2, b4.y, acc[2][1]);
            acc[2][2] = fmaf(a2, b4.z, acc[2][2]); acc[2][3] = fmaf(a2, b4.w, acc[2][3]);
            acc[3][0] = fmaf(a3, b4.x, acc[3][0]); acc[3][1] = fmaf(a3, b4.y, acc[3][1]);
            acc[3][2] = fmaf(a3, b4.z, acc[3][2]); acc[3][3] = fmaf(a3, b4.w, acc[3][3]);
        }
        __syncthreads();
    }
    #pragma unroll
    for (int i = 0; i < 4; ++i)
        *(float4*)(C + (long)(m0 + (ty << 2) + i) * 512 + n0 + (tx << 2)) =
            make_float4(acc[i][0], acc[i][1], acc[i][2], acc[i][3]);
}

// ---------------------------------------------------------------------------
// ln1: Z1 = LN(tmp + E + posenc)*g + be -> d_out f32 AND Z1b bf16 (ws).
// ---------------------------------------------------------------------------
__global__ __launch_bounds__(256) void ln1_kernel(const float* __restrict__ tmp,
                                                  const float* __restrict__ E,
                                                  const float* __restrict__ g,
                                                  const float* __restrict__ be,
                                                  float* __restrict__ out,
                                                  u16* __restrict__ z1b) {
    const int r = blockIdx.x, t = threadIdx.x;
    const long base = (long)r * 512;
    __shared__ float red[256];

    float v0 = tmp[base + t] + (float)((double)E[base + t] + posenc_d(r, t));
    float v1 = tmp[base + t + 256] +
               (float)((double)E[base + t + 256] + posenc_d(r, t + 256));

    red[t] = v0 + v1; __syncthreads();
    for (int s2 = 128; s2 > 0; s2 >>= 1) {
        if (t < s2) red[t] += red[t + s2];
        __syncthreads();
    }
    const float mean = red[0] * (1.0f / 512.0f);
    __syncthreads();
    float d0 = v0 - mean, d1 = v1 - mean;
    red[t] = d0 * d0 + d1 * d1; __syncthreads();
    for (int s2 = 128; s2 > 0; s2 >>= 1) {
        if (t < s2) red[t] += red[t + s2];
        __syncthreads();
    }
    const float rs = rsqrtf(red[0] * (1.0f / 512.0f) + LN_EPS);
    float o0 = d0 * rs * g[t] + be[t];
    float o1 = d1 * rs * g[t + 256] + be[t + 256];
    out[base + t] = o0;
    out[base + t + 256] = o1;
    z1b[base + t] = f2us(o0);
    z1b[base + t + 256] = f2us(o1);
}

// ---------------------------------------------------------------------------
// wtrans: dst[n][k] (bf16) = src[k][n] (f32).  grid (K/64, N/64).
// ---------------------------------------------------------------------------
__global__ __launch_bounds__(256) void wtrans_kernel(const float* __restrict__ src,
                                                     u16* __restrict__ dst,
                                                     int K, int N) {
    __shared__ float sT[64][65];
    const int t = threadIdx.x;
    const int k0 = blockIdx.x * 64, n0 = blockIdx.y * 64;
    #pragma unroll
    for (int c = 0; c < 4; ++c) {
        const int r = (t >> 4) + c * 16;
        float4 v = *(const float4*)(src + (long)(k0 + r) * N + n0 + ((t & 15) << 2));
        sT[r][((t & 15) << 2) + 0] = v.x;
        sT[r][((t & 15) << 2) + 1] = v.y;
        sT[r][((t & 15) << 2) + 2] = v.z;
        sT[r][((t & 15) << 2) + 3] = v.w;
    }
    __syncthreads();
    const int n = t >> 2, kc = (t & 3) << 4;
    #pragma unroll
    for (int u = 0; u < 4; ++u) {
        ushort4 o;
        o.x = f2us(sT[kc + 4 * u + 0][n]);
        o.y = f2us(sT[kc + 4 * u + 1][n]);
        o.z = f2us(sT[kc + 4 * u + 2][n]);
        o.w = f2us(sT[kc + 4 * u + 3][n]);
        *(ushort4*)(dst + (long)(n0 + n) * K + k0 + kc + 4 * u) = o;
    }
}

// ---------------------------------------------------------------------------
// ffn1 (MFMA): Hff = relu(Z1b @ W1t^T + b1) -> bf16.  A [4096][512] bf16,
// Bt [2048][512] bf16.  grid (32 nb, 16 mb) per 1024-row chunk.
// ---------------------------------------------------------------------------
__global__ __launch_bounds__(256) void ffn1_kernel(const u16* __restrict__ A,
                                                   const u16* __restrict__ Bt,
                                                   const float* __restrict__ b1,
                                                   u16* __restrict__ C,
                                                   int m_base) {
    __shared__ u16 sA[64][72], sB[64][72];
    const int t = threadIdx.x;
    const int w = t >> 6, l = t & 63, quad = l >> 4, l16 = l & 15;
    const int mw = w * 16;
    const int m0 = m_base + blockIdx.y * 64, n0 = blockIdx.x * 64;
    const int r = t >> 2, cc = (t & 3) << 4;

    float4v acc[4];
    #pragma unroll
    for (int nt = 0; nt < 4; ++nt) acc[nt] = (float4v){0.f, 0.f, 0.f, 0.f};

    for (int kt = 0; kt < 512; kt += 64) {
        const long aoff = (long)(m0 + r) * 512 + kt + cc;
        *(uint4*)&sA[r][cc]     = *(const uint4*)(A + aoff);
        *(uint4*)&sA[r][cc + 8] = *(const uint4*)(A + aoff + 8);
        const long boff = (long)(n0 + r) * 512 + kt + cc;
        *(uint4*)&sB[r][cc]     = *(const uint4*)(Bt + boff);
        *(uint4*)&sB[r][cc + 8] = *(const uint4*)(Bt + boff + 8);
        __syncthreads();
        #pragma unroll
        for (int kc = 0; kc < 2; ++kc) {
            short8 a = *(const short8*)&sA[mw + l16][kc * 32 + quad * 8];
            #pragma unroll
            for (int nt = 0; nt < 4; ++nt) {
                short8 b = *(const short8*)&sB[nt * 16 + l16][kc * 32 + quad * 8];
                acc[nt] = __builtin_amdgcn_mfma_f32_16x16x32_bf16(a, b, acc[nt], 0, 0, 0);
            }
        }
        __syncthreads();
    }
    #pragma unroll
    for (int rr = 0; rr < 4; ++rr) {
        const int row = blockIdx.y * 64 + mw + quad * 4 + rr;  // chunk-local
        #pragma unroll
        for (int nt = 0; nt < 4; ++nt) {
            const int col = n0 + nt * 16 + l16;
            float v = acc[nt][rr] + b1[col];
            C[(long)row * 2048 + col] = f2us(fmaxf(v, 0.0f));
        }
    }
}

// ---------------------------------------------------------------------------
// ffn2 (MFMA): U = Hff @ W2t^T + b2 -> f32.  A chunk [1024][2048] bf16,
// Bt [512][2048] bf16.  grid (8 nb, 16 mb).
// ---------------------------------------------------------------------------
__global__ __launch_bounds__(256) void ffn2_kernel(const u16* __restrict__ A,
                                                   const u16* __restrict__ Bt,
                                                   const float* __restrict__ b2,
                                                   float* __restrict__ U) {
    __shared__ u16 sA[64][72], sB[64][72];
    const int t = threadIdx.x;
    const int w = t >> 6, l = t & 63, quad = l >> 4, l16 = l & 15;
    const int mw = w * 16;
    const int m0 = blockIdx.y * 64, n0 = blockIdx.x * 64;
    const int r = t >> 2, cc = (t & 3) << 4;

    float4v acc[4];
    #pragma unroll
    for (int nt = 0; nt < 4; ++nt) acc[nt] = (float4v){0.f, 0.f, 0.f, 0.f};

    for (int kt = 0; kt < 2048; kt += 64) {
        const long aoff = (long)(m0 + r) * 2048 + kt + cc;
        *(uint4*)&sA[r][cc]     = *(const uint4*)(A + aoff);
        *(uint4*)&sA[r][cc + 8] = *(const uint4*)(A + aoff + 8);
        const long boff = (long)(n0 + r) * 2048 + kt + cc;
        *(uint4*)&sB[r][cc]     = *(const uint4*)(Bt + boff);
        *(uint4*)&sB[r][cc + 8] = *(const uint4*)(Bt + boff + 8);
        __syncthreads();
        #pragma unroll
        for (int kc = 0; kc < 2; ++kc) {
            short8 a = *(const short8*)&sA[mw + l16][kc * 32 + quad * 8];
            #pragma unroll
            for (int nt = 0; nt < 4; ++nt) {
                short8 b = *(const short8*)&sB[nt * 16 + l16][kc * 32 + quad * 8];
                acc[nt] = __builtin_amdgcn_mfma_f32_16x16x32_bf16(a, b, acc[nt], 0, 0, 0);
            }
        }
        __syncthreads();
    }
    #pragma unroll
    for (int rr = 0; rr < 4; ++rr) {
        const int row = m0 + mw + quad * 4 + rr;
        #pragma unroll
        for (int nt = 0; nt < 4; ++nt) {
            const int col = n0 + nt * 16 + l16;
            U[(long)row * 512 + col] = acc[nt][rr] + b2[col];
        }
    }
}

// ---------------------------------------------------------------------------
// ln2: out = LN(U + Z1)*g + be (in place over Z1 rows).
// ---------------------------------------------------------------------------
__global__ __launch_bounds__(256) void ln2_kernel(const float* __restrict__ U,
                                                  const float* __restrict__ Z1,
                                                  const float* __restrict__ g,
                                                  const float* __restrict__ be,
                                                  float* __restrict__ out) {
    const int r = blockIdx.x, t = threadIdx.x;
    const long base = (long)r * 512;
    __shared__ float red[256];

    float v0 = U[base + t] + Z1[base + t];
    float v1 = U[base + t + 256] + Z1[base + t + 256];

    red[t] = v0 + v1; __syncthreads();
    for (int s2 = 128; s2 > 0; s2 >>= 1) {
        if (t < s2) red[t] += red[t + s2];
        __syncthreads();
    }
    const float mean = red[0] * (1.0f / 512.0f);
    __syncthreads();
    float d0 = v0 - mean, d1 = v1 - mean;
    red[t] = d0 * d0 + d1 * d1; __syncthreads();
    for (int s2 = 128; s2 > 0; s2 >>= 1) {
        if (t < s2) red[t] += red[t + s2];
        __syncthreads();
    }
    const float rs = rsqrtf(red[0] * (1.0f / 512.0f) + LN_EPS);
    out[base + t] = d0 * rs * g[t] + be[t];
    out[base + t + 256] = d1 * rs * g[t + 256] + be[t + 256];
}

// ---------------------------------------------------------------------------
// ws timeline (max 14 MB):
//   attention: Khi @0 (4) | Klo @4 (4) | Vt @8 (4)
//   wo/ln1:    tmp @0 (8) | Z1b @8 (4)
//   FFN:       W1t @0 (2) | W2t @2 (2) | Hff @4 (4/chunk) | U @12 (2/chunk)
// d_out: Qcat -> Zcat -> Z1 -> out (race-free phase overwrites).
// ---------------------------------------------------------------------------
extern "C" void kernel_launch(void* const* d_in, const int* in_sizes, int n_in,
                              void* d_out, int out_size, void* d_ws, size_t ws_size,
                              hipStream_t stream) {
    float* outf = (float*)d_out;

    static const int exp_sizes[13] = {2097152, 262144, 262144, 262144, 262144,
                                      1048576, 2048, 1048576, 512, 512, 512,
                                      512, 512};
    bool ok = (n_in == 13) && (out_size == 2097152) &&
              (ws_size >= (14ull << 20));
    if (ok) for (int i = 0; i < 13; ++i) if (in_sizes[i] != exp_sizes[i]) ok = false;
    if (!ok) { sentinel_kernel<<<16, 256, 0, stream>>>(outf, 1000.0f); return; }

    const float* E   = (const float*)d_in[0];
    const float* Wq  = (const float*)d_in[1];
    const float* Wk  = (const float*)d_in[2];
    const float* Wv  = (const float*)d_in[3];
    const float* WO  = (const float*)d_in[4];
    const float* W1  = (const float*)d_in[5];
    const float* b1  = (const float*)d_in[6];
    const float* W2  = (const float*)d_in[7];
    const float* b2  = (const float*)d_in[8];
    const float* g1  = (const float*)d_in[9];
    const float* be1 = (const float*)d_in[10];
    const float* g2  = (const float*)d_in[11];
    const float* be2 = (const float*)d_in[12];

    char* base = (char*)d_ws;
    u16*   Khi = (u16*)base;                    // 4 MB
    u16*   Klo = (u16*)(base + (4l << 20));     // 4 MB
    u16*   Vt  = (u16*)(base + (8l << 20));     // 4 MB
    float* tmp = (float*)base;                  // 8 MB (K dead)
    u16*   Z1b = (u16*)(base + (8l << 20));     // 4 MB (Vt dead)
    u16*   W1t = (u16*)base;                    // 2 MB (tmp dead)
    u16*   W2t = (u16*)(base + (2l << 20));     // 2 MB
    u16*   Hff = (u16*)(base + (4l << 20));     // 4 MB / chunk
    float* U   = (float*)(base + (12l << 20));  // 2 MB / chunk

    qkv8_kernel<<<dim3(64, 24), 256, 0, stream>>>(E, Wq, Wk, Wv, outf,
                                                  Khi, Klo, Vt);
    flash8_kernel<<<dim3(64, 8), 256, 0, stream>>>(Khi, Klo, Vt, outf);
    wo_kernel<<<dim3(8, 64), 256, 0, stream>>>(outf, WO, tmp);
    ln1_kernel<<<4096, 256, 0, stream>>>(tmp, E, g1, be1, outf, Z1b);
    wtrans_kernel<<<dim3(8, 32), 256, 0, stream>>>(W1, W1t, 512, 2048);
    wtrans_kernel<<<dim3(32, 8), 256, 0, stream>>>(W2, W2t, 2048, 512);

    for (int c = 0; c < 4; ++c) {
        ffn1_kernel<<<dim3(32, 16), 256, 0, stream>>>(Z1b, W1t, b1, Hff,
                                                      c * 1024);
        ffn2_kernel<<<dim3(8, 16), 256, 0, stream>>>(Hff, W2t, b2, U);
        ln2_kernel<<<1024, 256, 0, stream>>>(U, outf + (long)c * 1024 * 512,
                                             g2, be2,
                                             outf + (long)c * 1024 * 512);
    }
}